// Round 12
// baseline (383.774 us; speedup 1.0000x reference)
//
#include <hip/hip_runtime.h>

// Established: all float inputs fp32, output fp32, mask int32. ws >= 256MB.
#define B_   4
#define S_   1024
#define D_   512
#define H_   8
#define DH_  64
#define L_   4
#define NTOK (B_ * S_)            // 4096 tokens
#define NT   (NTOK * D_)          // 2097152 elems per activation
#define DD   (D_ * D_)            // 262144 elems per weight matrix

typedef __attribute__((ext_vector_type(8))) short bf16x8;
typedef __attribute__((ext_vector_type(4))) float f32x4;

// async global->LDS, 16B per lane; LDS dest = wave-uniform base + lane*16
#define GLL(gp, lp)                                                            \
    __builtin_amdgcn_global_load_lds(                                          \
        (const __attribute__((address_space(1))) unsigned int*)(gp),           \
        (__attribute__((address_space(3))) unsigned int*)(lp), 16, 0, 0)

// ---------- bf16 helpers ----------
__device__ __forceinline__ float us2f(unsigned short u) {
    unsigned int v = ((unsigned int)u) << 16;
    return __uint_as_float(v);
}
__device__ __forceinline__ unsigned short f2us(float f) {
    unsigned int u = __float_as_uint(f);
    unsigned int r = (u + 0x7fffu + ((u >> 16) & 1u)) >> 16;
    return (unsigned short)r;
}

// fast tanh: 1 - 2/(exp2(2*log2e*z)+1); clamp avoids inf/inf. err ~1e-7.
__device__ __forceinline__ float tanh_fast(float z) {
    float zc = fminf(fmaxf(z, -20.f), 20.f);
    float e = __builtin_amdgcn_exp2f(zc * 2.8853900817779268f);
    return 1.f - 2.f * __builtin_amdgcn_rcpf(e + 1.f);
}

// standard uniform cubic B-spline M(t), support [-2,2]:
// M(t) = ((2-|t|)^3 - 4*max(1-|t|,0)^3) / 6
__device__ __forceinline__ float bspl3(float u) {
    float a = fabsf(u);
    float t2 = fmaxf(2.f - a, 0.f);
    float t1 = fmaxf(1.f - a, 0.f);
    float c2 = t2 * t2 * t2;
    float c1 = t1 * t1 * t1;
    return (c2 - 4.f * c1) * (1.f / 6.f);
}

// KAN inner on uniform knots h=2/7: B3[0] = M((xt+3/7)*3.5), B3[1] = M((xt+1/7)*3.5).
__device__ __forceinline__ float kan_fast(float zv, float c0, float c1) {
    float xt = tanh_fast(zv);
    float b0 = bspl3(__builtin_fmaf(xt, 3.5f, 1.5f));
    float b1 = bspl3(__builtin_fmaf(xt, 3.5f, 0.5f));
    return c0 * b0 + c1 * b1;
}

// ---------- merged upfront kernel: weight conversion + src copy + first LN1 ----------
struct PreArgs {
    const float* w[6];            // layer-0 base ptrs of the 6 weight tensors
    unsigned short* cw;           // 24*DD bf16 out
    const float* src;
    const float* ln1w;
    const float* ln1b;
    float* srcf;
    unsigned short* z;
};
__global__ __launch_bounds__(256) void pre_k(PreArgs a) {
    int bx = blockIdx.x;
    if (bx < 6144) {
        int y = bx >> 8;                     // matrix index 0..23 (= l*6 + t)
        int l = y / 6, tp = y - l * 6;
        int i = ((bx & 255) * 256 + threadIdx.x) * 4;
        float4 v = *(const float4*)(a.w[tp] + (size_t)l * DD + i);
        ushort4 o;
        o.x = f2us(v.x); o.y = f2us(v.y); o.z = f2us(v.z); o.w = f2us(v.w);
        *(ushort4*)(a.cw + (size_t)y * DD + i) = o;
    } else {
        int wv = threadIdx.x >> 6, lane = threadIdx.x & 63;
        int tok = (bx - 6144) * 4 + wv;
        const float* xr = a.src + (size_t)tok * D_;
        float v[8];
        float s = 0.f, s2 = 0.f;
#pragma unroll
        for (int i = 0; i < 8; ++i) {
            float t = xr[lane + 64 * i];
            v[i] = t; s += t; s2 += t * t;
        }
#pragma unroll
        for (int o = 1; o < 64; o <<= 1) { s += __shfl_xor(s, o); s2 += __shfl_xor(s2, o); }
        float mu = s * (1.f / D_);
        float var = s2 * (1.f / D_) - mu * mu;
        float rs = rsqrtf(var + 1e-5f);
#pragma unroll
        for (int i = 0; i < 8; ++i) {
            int d = lane + 64 * i;
            a.srcf[(size_t)tok * D_ + d] = v[i];
            a.z[(size_t)tok * D_ + d] = f2us((v[i] - mu) * rs * a.ln1w[d] + a.ln1b[d]);
        }
    }
}

// ---------- MFMA GEMM A: 128x128 tile, BK=64, dbuf 2-phase, COUNTED vmcnt ----------
struct MGemm128Args {
    const unsigned short* A;
    const unsigned short* W[4];
    const float* bias[4];
    unsigned short* C[4];
    int tflag[4];
};

__global__ __launch_bounds__(256) void mgemm128_k(MGemm128Args g) {
    __shared__ unsigned short As[2][128 * 64];
    __shared__ unsigned short Bs[2][128 * 64];
    int id = blockIdx.x + (blockIdx.y << 2) + (blockIdx.z << 7);   // 0..511
    int id2 = ((id & 7) << 6) + (id >> 3);                         // bijective (512 = 8*64)
    int z = id2 >> 7;
    const unsigned short* W = g.W[z];
    const float* bias = g.bias[z];
    unsigned short* C = g.C[z];
    int m0 = ((id2 >> 2) & 31) * 128, n0 = (id2 & 3) * 128;
    int t = threadIdx.x;
    int wave = t >> 6, lane = t & 63;
    int wm = (wave >> 1) * 64, wn = (wave & 1) * 64;
    int l15 = lane & 15, quad = lane >> 4;
    int srow = lane >> 3, schunk = lane & 7;    // staging: 8 rows x 8 chunks per GLL

    f32x4 acc[4][4];
#pragma unroll
    for (int i = 0; i < 4; ++i)
#pragma unroll
        for (int j = 0; j < 4; ++j)
#pragma unroll
            for (int r = 0; r < 4; ++r) acc[i][j][r] = 0.f;

    int rb = wave * 32;                          // each wave stages 32 rows of A and B
    int swz = l15 & 7;

    #define STAGE128(buf, k0)                                                       \
        do {                                                                        \
            _Pragma("unroll")                                                       \
            for (int g8 = 0; g8 < 4; ++g8) {                                        \
                int row0 = rb + g8 * 8;                                             \
                int row = row0 + srow;                                              \
                int cg = schunk ^ (row & 7);                                        \
                GLL(g.A + (size_t)(m0 + row) * D_ + (k0) + cg * 8, &As[buf][row0 * 64]); \
                GLL(W   + (size_t)(n0 + row) * D_ + (k0) + cg * 8, &Bs[buf][row0 * 64]); \
            }                                                                       \
        } while (0)

    STAGE128(0, 0);

    int cur = 0;
    for (int ks = 0; ks < 8; ++ks) {
        if (ks < 7) {
            STAGE128(cur ^ 1, (ks + 1) * 64);
            asm volatile("s_waitcnt vmcnt(8)" ::: "memory");   // tile ks landed; prefetch in flight
        } else {
            asm volatile("s_waitcnt vmcnt(0)" ::: "memory");
        }
        __builtin_amdgcn_s_barrier();
        __builtin_amdgcn_sched_barrier(0);
#pragma unroll
        for (int kc = 0; kc < 2; ++kc) {
            int ch = ((kc * 4 + quad) ^ swz) * 8;
            bf16x8 af[4], bfr[4];
#pragma unroll
            for (int mt = 0; mt < 4; ++mt)
                af[mt] = *(const bf16x8*)&As[cur][(wm + mt * 16 + l15) * 64 + ch];
#pragma unroll
            for (int nt = 0; nt < 4; ++nt)
                bfr[nt] = *(const bf16x8*)&Bs[cur][(wn + nt * 16 + l15) * 64 + ch];
#pragma unroll
            for (int mt = 0; mt < 4; ++mt)
#pragma unroll
                for (int nt = 0; nt < 4; ++nt)
                    acc[mt][nt] = __builtin_amdgcn_mfma_f32_16x16x32_bf16(
                        af[mt], bfr[nt], acc[mt][nt], 0, 0, 0);
        }
        __builtin_amdgcn_sched_barrier(0);
        __builtin_amdgcn_s_barrier();
        cur ^= 1;
    }
    #undef STAGE128

    if (g.tflag[z]) {
#pragma unroll
        for (int mt = 0; mt < 4; ++mt)
#pragma unroll
            for (int nt = 0; nt < 4; ++nt) {
                int n = n0 + wn + nt * 16 + l15;
                float bv = bias[n];
                int m = m0 + wm + mt * 16 + quad * 4;
                ushort4 pk;
                pk.x = f2us(acc[mt][nt][0] + bv);
                pk.y = f2us(acc[mt][nt][1] + bv);
                pk.z = f2us(acc[mt][nt][2] + bv);
                pk.w = f2us(acc[mt][nt][3] + bv);
                *(ushort4*)(C + ((size_t)(m >> 10) * 512 + n) * 1024 + (m & 1023)) = pk;
            }
    } else {
#pragma unroll
        for (int mt = 0; mt < 4; ++mt)
#pragma unroll
            for (int nt = 0; nt < 4; ++nt) {
                int n = n0 + wn + nt * 16 + l15;
                float bv = bias[n];
#pragma unroll
                for (int r = 0; r < 4; ++r) {
                    int m = m0 + wm + mt * 16 + quad * 4 + r;
                    C[(size_t)m * D_ + n] = f2us(acc[mt][nt][r] + bv);
                }
            }
    }
}

// ---------- FUSED double-GEMM block: Wo-GEMM + LN2 + KAN + oc-GEMM + LN3(+LN1) ----
// R6 structure widened to 16 WAVES (1024 threads): each wave owns a 32-row
// W-panel (nt=2, 4 GLL/step, vmcnt(4)); LDS footprint/layout/swizzles
// unchanged (145 KB, 1 block/CU). Doubles waves/SIMD 2->4 so the per-wave
// counted-vmcnt L2 wait hides under other waves' MFMA/VALU (the occupancy
// lever R7 missed: grid is fixed at 256, so more waves must come from a
// bigger block, not more blocks).
struct GFArgs {
    const unsigned short* A;      // zb (attn out, bf16)
    const unsigned short* W1;     // Wo (bf16)
    const unsigned short* W2;     // oc (bf16)
    const float* bias1;           // Wo bias
    const float* res;             // srcf (residual in)
    float* srcf;                  // residual out (LN3'd) [!LAST]
    float* outp;                  // final out [LAST]
    unsigned short* zb;           // LN1 out (next layer) [!LAST]
    const float* w2a; const float* b2a;   // LN2
    const float* w3;  const float* b3;    // LN3
    const float* w1n; const float* b1n;   // LN1 (next layer)
    const float* ic;              // inner_c
};

template <int LAST>
__global__ __launch_bounds__(1024) void gemmfused_k(GFArgs g) {
    __shared__ unsigned short Bs[2][512 * 64];   // 128 KB, per-wave 32-row panels
    __shared__ unsigned short Asm[16 * 512];     // 16 KB: phase1 A, then KAN inner
    __shared__ float redS[16][16];
    __shared__ float redS2[16][16];

    int m0 = blockIdx.x * 16;
    int t = threadIdx.x, wave = t >> 6, lane = t & 63;   // wave 0..15
    int l15 = lane & 15, quad = lane >> 4;
    int srow = lane >> 3, schunk = lane & 7;
    int swz = l15 & 7;

    // ---- prologue: A row (1/wave, full K, chunk-XOR swizzled) + W1 tiles 0,1
    {
        int r = wave;
        GLL(g.A + (size_t)(m0 + r) * D_ + (lane ^ (r & 7)) * 8, &Asm[r * 512]);
    }
    const unsigned short* Wp1 = g.W1 + (size_t)(wave * 32 + srow) * D_ + (schunk ^ srow) * 8;
#pragma unroll
    for (int g8 = 0; g8 < 4; ++g8)
        GLL(Wp1 + (size_t)g8 * 8 * D_, &Bs[0][(wave * 32 + g8 * 8) * 64]);
#pragma unroll
    for (int g8 = 0; g8 < 4; ++g8)
        GLL(Wp1 + 64 + (size_t)g8 * 8 * D_, &Bs[1][(wave * 32 + g8 * 8) * 64]);
    asm volatile("s_waitcnt vmcnt(8)" ::: "memory");   // A landed (oldest 1)
    __builtin_amdgcn_s_barrier();                       // Asm visible to all waves

    // per-wave 2-deep pipelined k-loop (8 steps of BK=64)
    #define KLOOP(accv, Wp)                                                           \
        for (int ks = 0; ks < 8; ++ks) {                                              \
            if (ks < 7) asm volatile("s_waitcnt vmcnt(4)" ::: "memory");              \
            else        asm volatile("s_waitcnt vmcnt(0)" ::: "memory");              \
            __builtin_amdgcn_sched_barrier(0);                                        \
            _Pragma("unroll")                                                         \
            for (int kc = 0; kc < 2; ++kc) {                                          \
                bf16x8 af = *(const bf16x8*)&Asm[l15 * 512 +                          \
                                                 ((ks * 8 + kc * 4 + quad) ^ swz) * 8];\
                _Pragma("unroll")                                                     \
                for (int nt = 0; nt < 2; ++nt) {                                      \
                    bf16x8 bf = *(const bf16x8*)&Bs[ks & 1][(wave * 32 + nt * 16 + l15) * 64 + \
                                                            ((kc * 4 + quad) ^ swz) * 8];      \
                    accv[nt] = __builtin_amdgcn_mfma_f32_16x16x32_bf16(af, bf, accv[nt], 0, 0, 0); \
                }                                                                     \
            }                                                                         \
            __builtin_amdgcn_sched_barrier(0);                                        \
            if (ks < 6) {                                                             \
                _Pragma("unroll")                                                     \
                for (int g8 = 0; g8 < 4; ++g8)                                        \
                    GLL(Wp + (ks + 2) * 64 + (size_t)g8 * 8 * D_,                     \
                        &Bs[ks & 1][(wave * 32 + g8 * 8) * 64]);                      \
            }                                                                         \
        }

    // row stats over vals[2][4] -> muv[4], rsv[4]
    #define ROWSTATS(vals, muv, rsv)                                                  \
        {                                                                             \
            __builtin_amdgcn_s_barrier();                                             \
            float s_[4] = {0.f, 0.f, 0.f, 0.f}, s2_[4] = {0.f, 0.f, 0.f, 0.f};        \
            _Pragma("unroll")                                                         \
            for (int nt = 0; nt < 2; ++nt)                                            \
                _Pragma("unroll")                                                     \
                for (int r = 0; r < 4; ++r) {                                         \
                    s_[r] += vals[nt][r]; s2_[r] += vals[nt][r] * vals[nt][r];        \
                }                                                                     \
            _Pragma("unroll")                                                         \
            for (int off = 1; off < 16; off <<= 1)                                    \
                _Pragma("unroll")                                                     \
                for (int r = 0; r < 4; ++r) {                                         \
                    s_[r] += __shfl_xor(s_[r], off); s2_[r] += __shfl_xor(s2_[r], off); \
                }                                                                     \
            if (l15 == 0) {                                                           \
                _Pragma("unroll")                                                     \
                for (int r = 0; r < 4; ++r) {                                         \
                    redS[quad * 4 + r][wave] = s_[r]; redS2[quad * 4 + r][wave] = s2_[r]; \
                }                                                                     \
            }                                                                         \
            asm volatile("s_waitcnt lgkmcnt(0)" ::: "memory");                        \
            __builtin_amdgcn_s_barrier();                                             \
            _Pragma("unroll")                                                         \
            for (int r = 0; r < 4; ++r) {                                             \
                float ss = 0.f, ss2 = 0.f;                                            \
                _Pragma("unroll")                                                     \
                for (int w = 0; w < 16; ++w) {                                        \
                    ss += redS[quad * 4 + r][w]; ss2 += redS2[quad * 4 + r][w];       \
                }                                                                     \
                muv[r] = ss * (1.f / D_);                                             \
                rsv[r] = rsqrtf(ss2 * (1.f / D_) - muv[r] * muv[r] + 1e-5f);          \
            }                                                                         \
        }

    // ---- phase 1: C1 = A @ Wo^T
    f32x4 acc[2];
#pragma unroll
    for (int nt = 0; nt < 2; ++nt)
#pragma unroll
        for (int r = 0; r < 4; ++r) acc[nt][r] = 0.f;
    KLOOP(acc, Wp1)

    // ---- issue phase-2 W staging NOW (hides under epilogue; Bs per-wave free)
    const unsigned short* Wp2 = g.W2 + (size_t)(wave * 32 + srow) * D_ + (schunk ^ srow) * 8;
#pragma unroll
    for (int g8 = 0; g8 < 4; ++g8)
        GLL(Wp2 + (size_t)g8 * 8 * D_, &Bs[0][(wave * 32 + g8 * 8) * 64]);
#pragma unroll
    for (int g8 = 0; g8 < 4; ++g8)
        GLL(Wp2 + 64 + (size_t)g8 * 8 * D_, &Bs[1][(wave * 32 + g8 * 8) * 64]);

    // hoist LN2 params + KAN coeffs per nt (latency hides under ROWSTATS)
    float c0v[2], c1v[2], w2v[2], b2v[2];
#pragma unroll
    for (int nt = 0; nt < 2; ++nt) {
        int n = wave * 32 + nt * 16 + l15;
        c0v[nt] = g.ic[n * 5 + 0];
        c1v[nt] = g.ic[n * 5 + 1];
        w2v[nt] = g.w2a[n];
        b2v[nt] = g.b2a[n];
    }

    // ---- epilogue 1: tv = acc + bias + res (regs only)
    float tv[2][4];
#pragma unroll
    for (int nt = 0; nt < 2; ++nt) {
        int n = wave * 32 + nt * 16 + l15;
        float bv = g.bias1[n];
#pragma unroll
        for (int r = 0; r < 4; ++r)
            tv[nt][r] = acc[nt][r] + bv + g.res[(size_t)(m0 + quad * 4 + r) * D_ + n];
    }

    float mu2[4], rs2[4];
    ROWSTATS(tv, mu2, rs2)

    // ---- KAN inner (closed-form uniform B-spline) -> Asm LDS (swizzled)
#pragma unroll
    for (int nt = 0; nt < 2; ++nt) {
        int n = wave * 32 + nt * 16 + l15;
        int gch = n >> 3;                      // global k-chunk
#pragma unroll
        for (int r = 0; r < 4; ++r) {
            int row = quad * 4 + r;
            float zv = (tv[nt][r] - mu2[r]) * rs2[r] * w2v[nt] + b2v[nt];
            Asm[row * 512 + (gch ^ (row & 7)) * 8 + (n & 7)] =
                f2us(kan_fast(zv, c0v[nt], c1v[nt]));
        }
    }
    asm volatile("s_waitcnt lgkmcnt(0)" ::: "memory");
    __builtin_amdgcn_s_barrier();              // inner visible to all waves
    __builtin_amdgcn_sched_barrier(0);

    // ---- phase 2: C2 = inner @ oc^T + tv
    f32x4 acc2[2];
#pragma unroll
    for (int nt = 0; nt < 2; ++nt)
#pragma unroll
        for (int r = 0; r < 4; ++r) acc2[nt][r] = 0.f;
    KLOOP(acc2, Wp2)

    float tv2[2][4];
#pragma unroll
    for (int nt = 0; nt < 2; ++nt)
#pragma unroll
        for (int r = 0; r < 4; ++r) tv2[nt][r] = acc2[nt][r] + tv[nt][r];

    float mu3[4], rs3[4];
    ROWSTATS(tv2, mu3, rs3)

    float yv[2][4];
#pragma unroll
    for (int nt = 0; nt < 2; ++nt) {
        int n = wave * 32 + nt * 16 + l15;
#pragma unroll
        for (int r = 0; r < 4; ++r) {
            float v = (tv2[nt][r] - mu3[r]) * rs3[r] * g.w3[n] + g.b3[n];
            yv[nt][r] = v;
            if (LAST) g.outp[(size_t)(m0 + quad * 4 + r) * D_ + n] = v;
            else      g.srcf[(size_t)(m0 + quad * 4 + r) * D_ + n] = v;
        }
    }

    if (!LAST) {
        float mu1[4], rs1[4];
        ROWSTATS(yv, mu1, rs1)
#pragma unroll
        for (int nt = 0; nt < 2; ++nt) {
            int n = wave * 32 + nt * 16 + l15;
#pragma unroll
            for (int r = 0; r < 4; ++r)
                g.zb[(size_t)(m0 + quad * 4 + r) * D_ + n] =
                    f2us((yv[nt][r] - mu1[r]) * rs1[r] * g.w1n[n] + g.b1n[n]);
        }
    }
    #undef KLOOP
    #undef ROWSTATS
}

// ---------- MFMA flash attention, SWAPPED QK^T, packed P-writes ----------
__global__ __launch_bounds__(256) void attn_k(const unsigned short* __restrict__ Q,
                                              const unsigned short* __restrict__ K,
                                              const unsigned short* __restrict__ vt,
                                              const unsigned short* __restrict__ R,
                                              const int* __restrict__ mask,
                                              unsigned short* __restrict__ O) {
    __shared__ unsigned short Ks[2][64 * 64];
    __shared__ unsigned short Vts[2][64 * 64];
    __shared__ unsigned short Ps[4][16][72];
    __shared__ float Ms[1024];

    int bh = blockIdx.x;
    int b = bh >> 3, h = bh & 7;
    int qt0 = blockIdx.y * 64;
    int t = threadIdx.x, wave = t >> 6, lane = t & 63;
    int l15 = lane & 15, quad = lane >> 4;
    int qw0 = qt0 + wave * 16;

    const unsigned short* Qrow = Q + ((size_t)(b * S_ + qw0 + l15) * H_ + h) * DH_;
    bf16x8 qf[2];
    qf[0] = *(const bf16x8*)(Qrow + quad * 8);
    qf[1] = *(const bf16x8*)(Qrow + 32 + quad * 8);

#pragma unroll
    for (int u = 0; u < 4; ++u)
        Ms[u * 256 + t] = mask[b * S_ + u * 256 + t] ? 0.f : -1e10f;
    asm volatile("s_waitcnt lgkmcnt(0)" ::: "memory");

    float lsum = 0.f;                    // sum over k for q = l15
    f32x4 acc_o[4];
#pragma unroll
    for (int dt = 0; dt < 4; ++dt)
#pragma unroll
        for (int r = 0; r < 4; ++r) acc_o[dt][r] = 0.f;

    int lro = lane >> 3;
    int cglob = (lane & 7) ^ lro;
    const unsigned short* kgp0 =
        K + ((size_t)(b * S_ + wave * 16 + lro) * H_ + h) * DH_ + cglob * 8;
    const unsigned short* vgp0 =
        vt + (size_t)(b * 512 + h * 64 + wave * 16 + lro) * 1024 + cglob * 8;
    int swz = l15 & 7;
    const float SC = 0.125f * 1.44269504089f;

    #define ASTAGE(buf, kt)                                                         \
        do {                                                                        \
            GLL(kgp0 + (size_t)(kt) * 64 * 512,           &Ks[buf][(wave * 16) * 64]);     \
            GLL(kgp0 + (size_t)(kt) * 64 * 512 + 8 * 512, &Ks[buf][(wave * 16 + 8) * 64]); \
            GLL(vgp0 + (kt) * 64,                         &Vts[buf][(wave * 16) * 64]);    \
            GLL(vgp0 + (kt) * 64 + 8 * 1024,              &Vts[buf][(wave * 16 + 8) * 64]);\
        } while (0)

    ASTAGE(0, 0);

    int cur = 0;
    for (int kt = 0; kt < 16; ++kt) {
        if (kt < 15) {
            ASTAGE(cur ^ 1, kt + 1);
            asm volatile("s_waitcnt vmcnt(4)" ::: "memory");
        } else {
            asm volatile("s_waitcnt vmcnt(0)" ::: "memory");
        }
        __builtin_amdgcn_s_barrier();
        __builtin_amdgcn_sched_barrier(0);

        // S^T = K @ Q^T
        f32x4 accs[4];
#pragma unroll
        for (int jt = 0; jt < 4; ++jt)
#pragma unroll
            for (int r = 0; r < 4; ++r) accs[jt][r] = 0.f;
        __builtin_amdgcn_s_setprio(1);
#pragma unroll
        for (int kc = 0; kc < 2; ++kc) {
            int ch = ((kc * 4 + quad) ^ swz) * 8;
#pragma unroll
            for (int jt = 0; jt < 4; ++jt) {
                bf16x8 kf = *(const bf16x8*)&Ks[cur][(jt * 16 + l15) * 64 + ch];
                accs[jt] = __builtin_amdgcn_mfma_f32_16x16x32_bf16(kf, qf[kc], accs[jt], 0, 0, 0);
            }
        }
        __builtin_amdgcn_s_setprio(0);

        // softmax-lite; pack 4 bf16 -> one b64 write per jt
#pragma unroll
        for (int jt = 0; jt < 4; ++jt) {
            int kb = kt * 64 + jt * 16 + quad * 4;
            float p0 = __builtin_amdgcn_exp2f(accs[jt][0] * SC + Ms[kb + 0]);
            float p1 = __builtin_amdgcn_exp2f(accs[jt][1] * SC + Ms[kb + 1]);
            float p2 = __builtin_amdgcn_exp2f(accs[jt][2] * SC + Ms[kb + 2]);
            float p3 = __builtin_amdgcn_exp2f(accs[jt][3] * SC + Ms[kb + 3]);
            lsum += (p0 + p1) + (p2 + p3);
            uint2 pk;
            pk.x = __builtin_amdgcn_perm(__float_as_uint(p1), __float_as_uint(p0), 0x07060302u);
            pk.y = __builtin_amdgcn_perm(__float_as_uint(p3), __float_as_uint(p2), 0x07060302u);
            *(uint2*)&Ps[wave][l15][jt * 16 + quad * 4] = pk;
        }

        // O += P @ V
        __builtin_amdgcn_s_setprio(1);
#pragma unroll
        for (int kc = 0; kc < 2; ++kc) {
            bf16x8 pf = *(const bf16x8*)&Ps[wave][l15][kc * 32 + quad * 8];
            int ch = ((kc * 4 + quad) ^ swz) * 8;
#pragma unroll
            for (int dt = 0; dt < 4; ++dt) {
                bf16x8 vf = *(const bf16x8*)&Vts[cur][(dt * 16 + l15) * 64 + ch];
                acc_o[dt] = __builtin_amdgcn_mfma_f32_16x16x32_bf16(pf, vf, acc_o[dt], 0, 0, 0);
            }
        }
        __builtin_amdgcn_s_setprio(0);

        __builtin_amdgcn_sched_barrier(0);
        __builtin_amdgcn_s_barrier();
        cur ^= 1;
    }
    #undef ASTAGE

    lsum += __shfl_xor(lsum, 16);
    lsum += __shfl_xor(lsum, 32);

#pragma unroll
    for (int r = 0; r < 4; ++r) {
        int qq = quad * 4 + r;
        int q = qw0 + qq;
        float inv = 1.f / __shfl(lsum, qq);
        const unsigned short* Rr = R + ((size_t)(b * S_ + q) * H_ + h) * DH_;
        unsigned short* Or = O + ((size_t)(b * S_ + q) * H_ + h) * DH_;
#pragma unroll
        for (int dt = 0; dt < 4; ++dt) {
            int d = dt * 16 + l15;
            Or[d] = f2us(acc_o[dt][r] * inv * us2f(Rr[d]));
        }
    }
}

extern "C" void kernel_launch(void* const* d_in, const int* in_sizes, int n_in,
                              void* d_out, int out_size, void* d_ws, size_t ws_size,
                              hipStream_t stream) {
    const float* src  = (const float*)d_in[0];
    const float* ln1w = (const float*)d_in[1];
    const float* ln1b = (const float*)d_in[2];
    const float* ln2w = (const float*)d_in[3];
    const float* ln2b = (const float*)d_in[4];
    const float* ln3w = (const float*)d_in[5];
    const float* ln3b = (const float*)d_in[6];
    const float* wq   = (const float*)d_in[7];
    const float* wqb  = (const float*)d_in[8];
    const float* wk   = (const float*)d_in[9];
    const float* wkb  = (const float*)d_in[10];
    const float* wv   = (const float*)d_in[11];
    const float* wvb  = (const float*)d_in[12];
    const float* wr   = (const float*)d_in[13];
    const float* wrb  = (const float*)d_in[14];
    const float* wo   = (const float*)d_in[15];
    const float* wob  = (const float*)d_in[16];
    const float* ic   = (const float*)d_in[17];
    const float* oc   = (const float*)d_in[18];
    const int* mask   = (const int*)d_in[19];
    float* out = (float*)d_out;

    // ws: srcf 8MB | zb 4 | q 4 | k 4 | v 4 | r 4 | cw24 12  = 40MB
    float* srcf = (float*)d_ws;
    unsigned short* zb = (unsigned short*)(srcf + NT);
    unsigned short* qb = zb + NT;
    unsigned short* kb = qb + NT;
    unsigned short* vb = kb + NT;   // V transposed: vt[(b*512+h*64+d)*1024+s]
    unsigned short* rb = vb + NT;
    unsigned short* cw = rb + NT;   // 24 matrices: (l*6 + {q,k,v,r,o,oc}) * DD

    PreArgs pa;
    pa.w[0] = wq; pa.w[1] = wk; pa.w[2] = wv;
    pa.w[3] = wr; pa.w[4] = wo; pa.w[5] = oc;
    pa.cw = cw; pa.src = src; pa.ln1w = ln1w; pa.ln1b = ln1b;
    pa.srcf = srcf; pa.z = zb;
    pre_k<<<dim3(6144 + NTOK / 4), dim3(256), 0, stream>>>(pa);

    for (int l = 0; l < L_; ++l) {
        unsigned short* cwl = cw + (size_t)l * 6 * DD;

        MGemm128Args ga;
        ga.A = zb;
        ga.W[0] = cwl + 0 * DD; ga.bias[0] = wqb + l * D_; ga.C[0] = qb; ga.tflag[0] = 0;
        ga.W[1] = cwl + 1 * DD; ga.bias[1] = wkb + l * D_; ga.C[1] = kb; ga.tflag[1] = 0;
        ga.W[2] = cwl + 2 * DD; ga.bias[2] = wvb + l * D_; ga.C[2] = vb; ga.tflag[2] = 1;
        ga.W[3] = cwl + 3 * DD; ga.bias[3] = wrb + l * D_; ga.C[3] = rb; ga.tflag[3] = 0;
        mgemm128_k<<<dim3(4, 32, 4), dim3(256), 0, stream>>>(ga);

        attn_k<<<dim3(32, 16), dim3(256), 0, stream>>>(qb, kb, vb, rb, mask, zb);

        GFArgs gf;
        gf.A = zb; gf.W1 = cwl + 4 * DD; gf.W2 = cwl + 5 * DD;
        gf.bias1 = wob + l * D_; gf.res = srcf;
        gf.srcf = srcf; gf.outp = out; gf.zb = zb;
        gf.w2a = ln2w + l * D_; gf.b2a = ln2b + l * D_;
        gf.w3 = ln3w + l * D_; gf.b3 = ln3b + l * D_;
        gf.w1n = (l < L_ - 1) ? ln1w + (l + 1) * D_ : nullptr;
        gf.b1n = (l < L_ - 1) ? ln1b + (l + 1) * D_ : nullptr;
        gf.ic = ic + (size_t)l * D_ * 5;

        if (l < L_ - 1)
            gemmfused_k<0><<<dim3(NTOK / 16), dim3(1024), 0, stream>>>(gf);
        else
            gemmfused_k<1><<<dim3(NTOK / 16), dim3(1024), 0, stream>>>(gf);
    }
}

// Round 13
// 357.347 us; speedup vs baseline: 1.0740x; 1.0740x over previous
//
#include <hip/hip_runtime.h>

// Established: all float inputs fp32, output fp32, mask int32. ws >= 256MB.
#define B_   4
#define S_   1024
#define D_   512
#define H_   8
#define DH_  64
#define L_   4
#define NTOK (B_ * S_)            // 4096 tokens
#define NT   (NTOK * D_)          // 2097152 elems per activation
#define DD   (D_ * D_)            // 262144 elems per weight matrix

typedef __attribute__((ext_vector_type(8))) short bf16x8;
typedef __attribute__((ext_vector_type(4))) float f32x4;

// async global->LDS, 16B per lane; LDS dest = wave-uniform base + lane*16
#define GLL(gp, lp)                                                            \
    __builtin_amdgcn_global_load_lds(                                          \
        (const __attribute__((address_space(1))) unsigned int*)(gp),           \
        (__attribute__((address_space(3))) unsigned int*)(lp), 16, 0, 0)

// ---------- bf16 helpers ----------
__device__ __forceinline__ float us2f(unsigned short u) {
    unsigned int v = ((unsigned int)u) << 16;
    return __uint_as_float(v);
}
__device__ __forceinline__ unsigned short f2us(float f) {
    unsigned int u = __float_as_uint(f);
    unsigned int r = (u + 0x7fffu + ((u >> 16) & 1u)) >> 16;
    return (unsigned short)r;
}

// fast tanh: 1 - 2/(exp2(2*log2e*z)+1); clamp avoids inf/inf. err ~1e-7.
__device__ __forceinline__ float tanh_fast(float z) {
    float zc = fminf(fmaxf(z, -20.f), 20.f);
    float e = __builtin_amdgcn_exp2f(zc * 2.8853900817779268f);
    return 1.f - 2.f * __builtin_amdgcn_rcpf(e + 1.f);
}

// standard uniform cubic B-spline M(t), support [-2,2]:
// M(t) = ((2-|t|)^3 - 4*max(1-|t|,0)^3) / 6
__device__ __forceinline__ float bspl3(float u) {
    float a = fabsf(u);
    float t2 = fmaxf(2.f - a, 0.f);
    float t1 = fmaxf(1.f - a, 0.f);
    float c2 = t2 * t2 * t2;
    float c1 = t1 * t1 * t1;
    return (c2 - 4.f * c1) * (1.f / 6.f);
}

// KAN inner on uniform knots h=2/7: B3[0] = M((xt+3/7)*3.5), B3[1] = M((xt+1/7)*3.5).
// Verified vs Cox-de-Boor at xt=0 (0.0208333 / 0.4791666) and edges xt=+-1 (0,0).
__device__ __forceinline__ float kan_fast(float zv, float c0, float c1) {
    float xt = tanh_fast(zv);
    float b0 = bspl3(__builtin_fmaf(xt, 3.5f, 1.5f));
    float b1 = bspl3(__builtin_fmaf(xt, 3.5f, 0.5f));
    return c0 * b0 + c1 * b1;
}

// ---------- merged upfront kernel: weight conversion + src copy + first LN1 ----------
struct PreArgs {
    const float* w[6];            // layer-0 base ptrs of the 6 weight tensors
    unsigned short* cw;           // 24*DD bf16 out
    const float* src;
    const float* ln1w;
    const float* ln1b;
    float* srcf;
    unsigned short* z;
};
__global__ __launch_bounds__(256) void pre_k(PreArgs a) {
    int bx = blockIdx.x;
    if (bx < 6144) {
        int y = bx >> 8;                     // matrix index 0..23 (= l*6 + t)
        int l = y / 6, tp = y - l * 6;
        int i = ((bx & 255) * 256 + threadIdx.x) * 4;
        float4 v = *(const float4*)(a.w[tp] + (size_t)l * DD + i);
        ushort4 o;
        o.x = f2us(v.x); o.y = f2us(v.y); o.z = f2us(v.z); o.w = f2us(v.w);
        *(ushort4*)(a.cw + (size_t)y * DD + i) = o;
    } else {
        int wv = threadIdx.x >> 6, lane = threadIdx.x & 63;
        int tok = (bx - 6144) * 4 + wv;
        const float* xr = a.src + (size_t)tok * D_;
        float v[8];
        float s = 0.f, s2 = 0.f;
#pragma unroll
        for (int i = 0; i < 8; ++i) {
            float t = xr[lane + 64 * i];
            v[i] = t; s += t; s2 += t * t;
        }
#pragma unroll
        for (int o = 1; o < 64; o <<= 1) { s += __shfl_xor(s, o); s2 += __shfl_xor(s2, o); }
        float mu = s * (1.f / D_);
        float var = s2 * (1.f / D_) - mu * mu;
        float rs = rsqrtf(var + 1e-5f);
#pragma unroll
        for (int i = 0; i < 8; ++i) {
            int d = lane + 64 * i;
            a.srcf[(size_t)tok * D_ + d] = v[i];
            a.z[(size_t)tok * D_ + d] = f2us((v[i] - mu) * rs * a.ln1w[d] + a.ln1b[d]);
        }
    }
}

// ---------- MFMA GEMM A: 128x128 tile, BK=64, dbuf 2-phase, COUNTED vmcnt ----------
struct MGemm128Args {
    const unsigned short* A;
    const unsigned short* W[4];
    const float* bias[4];
    unsigned short* C[4];
    int tflag[4];
};

__global__ __launch_bounds__(256) void mgemm128_k(MGemm128Args g) {
    __shared__ unsigned short As[2][128 * 64];
    __shared__ unsigned short Bs[2][128 * 64];
    int id = blockIdx.x + (blockIdx.y << 2) + (blockIdx.z << 7);   // 0..511
    int id2 = ((id & 7) << 6) + (id >> 3);                         // bijective (512 = 8*64)
    int z = id2 >> 7;
    const unsigned short* W = g.W[z];
    const float* bias = g.bias[z];
    unsigned short* C = g.C[z];
    int m0 = ((id2 >> 2) & 31) * 128, n0 = (id2 & 3) * 128;
    int t = threadIdx.x;
    int wave = t >> 6, lane = t & 63;
    int wm = (wave >> 1) * 64, wn = (wave & 1) * 64;
    int l15 = lane & 15, quad = lane >> 4;
    int srow = lane >> 3, schunk = lane & 7;    // staging: 8 rows x 8 chunks per GLL

    f32x4 acc[4][4];
#pragma unroll
    for (int i = 0; i < 4; ++i)
#pragma unroll
        for (int j = 0; j < 4; ++j)
#pragma unroll
            for (int r = 0; r < 4; ++r) acc[i][j][r] = 0.f;

    int rb = wave * 32;                          // each wave stages 32 rows of A and B
    int swz = l15 & 7;

    #define STAGE128(buf, k0)                                                       \
        do {                                                                        \
            _Pragma("unroll")                                                       \
            for (int g8 = 0; g8 < 4; ++g8) {                                        \
                int row0 = rb + g8 * 8;                                             \
                int row = row0 + srow;                                              \
                int cg = schunk ^ (row & 7);                                        \
                GLL(g.A + (size_t)(m0 + row) * D_ + (k0) + cg * 8, &As[buf][row0 * 64]); \
                GLL(W   + (size_t)(n0 + row) * D_ + (k0) + cg * 8, &Bs[buf][row0 * 64]); \
            }                                                                       \
        } while (0)

    STAGE128(0, 0);

    int cur = 0;
    for (int ks = 0; ks < 8; ++ks) {
        if (ks < 7) {
            STAGE128(cur ^ 1, (ks + 1) * 64);
            asm volatile("s_waitcnt vmcnt(8)" ::: "memory");   // tile ks landed; prefetch in flight
        } else {
            asm volatile("s_waitcnt vmcnt(0)" ::: "memory");
        }
        __builtin_amdgcn_s_barrier();
        __builtin_amdgcn_sched_barrier(0);
#pragma unroll
        for (int kc = 0; kc < 2; ++kc) {
            int ch = ((kc * 4 + quad) ^ swz) * 8;
            bf16x8 af[4], bfr[4];
#pragma unroll
            for (int mt = 0; mt < 4; ++mt)
                af[mt] = *(const bf16x8*)&As[cur][(wm + mt * 16 + l15) * 64 + ch];
#pragma unroll
            for (int nt = 0; nt < 4; ++nt)
                bfr[nt] = *(const bf16x8*)&Bs[cur][(wn + nt * 16 + l15) * 64 + ch];
#pragma unroll
            for (int mt = 0; mt < 4; ++mt)
#pragma unroll
                for (int nt = 0; nt < 4; ++nt)
                    acc[mt][nt] = __builtin_amdgcn_mfma_f32_16x16x32_bf16(
                        af[mt], bfr[nt], acc[mt][nt], 0, 0, 0);
        }
        __builtin_amdgcn_sched_barrier(0);
        __builtin_amdgcn_s_barrier();
        cur ^= 1;
    }
    #undef STAGE128

    if (g.tflag[z]) {
#pragma unroll
        for (int mt = 0; mt < 4; ++mt)
#pragma unroll
            for (int nt = 0; nt < 4; ++nt) {
                int n = n0 + wn + nt * 16 + l15;
                float bv = bias[n];
                int m = m0 + wm + mt * 16 + quad * 4;
                ushort4 pk;
                pk.x = f2us(acc[mt][nt][0] + bv);
                pk.y = f2us(acc[mt][nt][1] + bv);
                pk.z = f2us(acc[mt][nt][2] + bv);
                pk.w = f2us(acc[mt][nt][3] + bv);
                *(ushort4*)(C + ((size_t)(m >> 10) * 512 + n) * 1024 + (m & 1023)) = pk;
            }
    } else {
#pragma unroll
        for (int mt = 0; mt < 4; ++mt)
#pragma unroll
            for (int nt = 0; nt < 4; ++nt) {
                int n = n0 + wn + nt * 16 + l15;
                float bv = bias[n];
#pragma unroll
                for (int r = 0; r < 4; ++r) {
                    int m = m0 + wm + mt * 16 + quad * 4 + r;
                    C[(size_t)m * D_ + n] = f2us(acc[mt][nt][r] + bv);
                }
            }
    }
}

// ---------- FUSED double-GEMM block: Wo-GEMM + LN2 + KAN + oc-GEMM + LN3(+LN1) ----
// (R6 structure: per-wave 64-row W panels, BK=64 double-buffer, 2-deep counted
// vmcnt; LN stats in dedicated LDS; phase-2 W staging overlaps the epilogue;
// closed-form uniform-knot spline + fast tanh in the KAN epilogue.)
struct GFArgs {
    const unsigned short* A;      // zb (attn out, bf16)
    const unsigned short* W1;     // Wo (bf16)
    const unsigned short* W2;     // oc (bf16)
    const float* bias1;           // Wo bias
    const float* res;             // srcf (residual in)
    float* srcf;                  // residual out (LN3'd) [!LAST]
    float* outp;                  // final out [LAST]
    unsigned short* zb;           // LN1 out (next layer) [!LAST]
    const float* w2a; const float* b2a;   // LN2
    const float* w3;  const float* b3;    // LN3
    const float* w1n; const float* b1n;   // LN1 (next layer)
    const float* ic;              // inner_c
};

template <int LAST>
__global__ __launch_bounds__(512) void gemmfused_k(GFArgs g) {
    __shared__ unsigned short Bs[2][512 * 64];   // 128 KB, per-wave 64-row panels
    __shared__ unsigned short Asm[16 * 512];     // 16 KB: phase1 A, then KAN inner
    __shared__ float redS[16][8];
    __shared__ float redS2[16][8];

    int m0 = blockIdx.x * 16;
    int t = threadIdx.x, wave = t >> 6, lane = t & 63;
    int l15 = lane & 15, quad = lane >> 4;
    int srow = lane >> 3, schunk = lane & 7;
    int swz = l15 & 7;

    // ---- prologue: A rows (2/wave, full K, chunk-XOR swizzled) + W1 tiles 0,1
#pragma unroll
    for (int rr = 0; rr < 2; ++rr) {
        int r = wave * 2 + rr;
        GLL(g.A + (size_t)(m0 + r) * D_ + (lane ^ (r & 7)) * 8, &Asm[r * 512]);
    }
    const unsigned short* Wp1 = g.W1 + (size_t)(wave * 64 + srow) * D_ + (schunk ^ srow) * 8;
#pragma unroll
    for (int g8 = 0; g8 < 8; ++g8)
        GLL(Wp1 + (size_t)g8 * 8 * D_, &Bs[0][(wave * 64 + g8 * 8) * 64]);
#pragma unroll
    for (int g8 = 0; g8 < 8; ++g8)
        GLL(Wp1 + 64 + (size_t)g8 * 8 * D_, &Bs[1][(wave * 64 + g8 * 8) * 64]);
    asm volatile("s_waitcnt vmcnt(16)" ::: "memory");   // A landed (oldest 2)
    __builtin_amdgcn_s_barrier();                        // Asm visible to all waves

    // per-wave 2-deep pipelined k-loop (8 steps of BK=64)
    #define KLOOP(accv, Wp)                                                           \
        for (int ks = 0; ks < 8; ++ks) {                                              \
            if (ks < 7) asm volatile("s_waitcnt vmcnt(8)" ::: "memory");              \
            else        asm volatile("s_waitcnt vmcnt(0)" ::: "memory");              \
            __builtin_amdgcn_sched_barrier(0);                                        \
            _Pragma("unroll")                                                         \
            for (int kc = 0; kc < 2; ++kc) {                                          \
                bf16x8 af = *(const bf16x8*)&Asm[l15 * 512 +                          \
                                                 ((ks * 8 + kc * 4 + quad) ^ swz) * 8];\
                _Pragma("unroll")                                                     \
                for (int nt = 0; nt < 4; ++nt) {                                      \
                    bf16x8 bf = *(const bf16x8*)&Bs[ks & 1][(wave * 64 + nt * 16 + l15) * 64 + \
                                                            ((kc * 4 + quad) ^ swz) * 8];      \
                    accv[nt] = __builtin_amdgcn_mfma_f32_16x16x32_bf16(af, bf, accv[nt], 0, 0, 0); \
                }                                                                     \
            }                                                                         \
            __builtin_amdgcn_sched_barrier(0);                                        \
            if (ks < 6) {                                                             \
                _Pragma("unroll")                                                     \
                for (int g8 = 0; g8 < 8; ++g8)                                        \
                    GLL(Wp + (ks + 2) * 64 + (size_t)g8 * 8 * D_,                     \
                        &Bs[ks & 1][(wave * 64 + g8 * 8) * 64]);                      \
            }                                                                         \
        }

    // row stats over vals[4][4] -> muv[4], rsv[4]
    #define ROWSTATS(vals, muv, rsv)                                                  \
        {                                                                             \
            __builtin_amdgcn_s_barrier();                                             \
            float s_[4] = {0.f, 0.f, 0.f, 0.f}, s2_[4] = {0.f, 0.f, 0.f, 0.f};        \
            _Pragma("unroll")                                                         \
            for (int nt = 0; nt < 4; ++nt)                                            \
                _Pragma("unroll")                                                     \
                for (int r = 0; r < 4; ++r) {                                         \
                    s_[r] += vals[nt][r]; s2_[r] += vals[nt][r] * vals[nt][r];        \
                }                                                                     \
            _Pragma("unroll")                                                         \
            for (int off = 1; off < 16; off <<= 1)                                    \
                _Pragma("unroll")                                                     \
                for (int r = 0; r < 4; ++r) {                                         \
                    s_[r] += __shfl_xor(s_[r], off); s2_[r] += __shfl_xor(s2_[r], off); \
                }                                                                     \
            if (l15 == 0) {                                                           \
                _Pragma("unroll")                                                     \
                for (int r = 0; r < 4; ++r) {                                         \
                    redS[quad * 4 + r][wave] = s_[r]; redS2[quad * 4 + r][wave] = s2_[r]; \
                }                                                                     \
            }                                                                         \
            asm volatile("s_waitcnt lgkmcnt(0)" ::: "memory");                        \
            __builtin_amdgcn_s_barrier();                                             \
            _Pragma("unroll")                                                         \
            for (int r = 0; r < 4; ++r) {                                             \
                float ss = 0.f, ss2 = 0.f;                                            \
                _Pragma("unroll")                                                     \
                for (int w = 0; w < 8; ++w) {                                         \
                    ss += redS[quad * 4 + r][w]; ss2 += redS2[quad * 4 + r][w];       \
                }                                                                     \
                muv[r] = ss * (1.f / D_);                                             \
                rsv[r] = rsqrtf(ss2 * (1.f / D_) - muv[r] * muv[r] + 1e-5f);          \
            }                                                                         \
        }

    // ---- phase 1: C1 = A @ Wo^T
    f32x4 acc[4];
#pragma unroll
    for (int nt = 0; nt < 4; ++nt)
#pragma unroll
        for (int r = 0; r < 4; ++r) acc[nt][r] = 0.f;
    KLOOP(acc, Wp1)

    // ---- issue phase-2 W staging NOW (hides under epilogue; Bs per-wave free)
    const unsigned short* Wp2 = g.W2 + (size_t)(wave * 64 + srow) * D_ + (schunk ^ srow) * 8;
#pragma unroll
    for (int g8 = 0; g8 < 8; ++g8)
        GLL(Wp2 + (size_t)g8 * 8 * D_, &Bs[0][(wave * 64 + g8 * 8) * 64]);
#pragma unroll
    for (int g8 = 0; g8 < 8; ++g8)
        GLL(Wp2 + 64 + (size_t)g8 * 8 * D_, &Bs[1][(wave * 64 + g8 * 8) * 64]);

    // hoist LN2 params + KAN coeffs per nt (latency hides under ROWSTATS)
    float c0v[4], c1v[4], w2v[4], b2v[4];
#pragma unroll
    for (int nt = 0; nt < 4; ++nt) {
        int n = wave * 64 + nt * 16 + l15;
        c0v[nt] = g.ic[n * 5 + 0];
        c1v[nt] = g.ic[n * 5 + 1];
        w2v[nt] = g.w2a[n];
        b2v[nt] = g.b2a[n];
    }

    // ---- epilogue 1: tv = acc + bias + res (regs only)
    float tv[4][4];
#pragma unroll
    for (int nt = 0; nt < 4; ++nt) {
        int n = wave * 64 + nt * 16 + l15;
        float bv = g.bias1[n];
#pragma unroll
        for (int r = 0; r < 4; ++r)
            tv[nt][r] = acc[nt][r] + bv + g.res[(size_t)(m0 + quad * 4 + r) * D_ + n];
    }

    float mu2[4], rs2[4];
    ROWSTATS(tv, mu2, rs2)

    // ---- KAN inner (closed-form uniform B-spline) -> Asm LDS (swizzled)
#pragma unroll
    for (int nt = 0; nt < 4; ++nt) {
        int n = wave * 64 + nt * 16 + l15;
        int gch = n >> 3;                      // global k-chunk
#pragma unroll
        for (int r = 0; r < 4; ++r) {
            int row = quad * 4 + r;
            float zv = (tv[nt][r] - mu2[r]) * rs2[r] * w2v[nt] + b2v[nt];
            Asm[row * 512 + (gch ^ (row & 7)) * 8 + (n & 7)] =
                f2us(kan_fast(zv, c0v[nt], c1v[nt]));
        }
    }
    asm volatile("s_waitcnt lgkmcnt(0)" ::: "memory");
    __builtin_amdgcn_s_barrier();              // inner visible to all waves
    __builtin_amdgcn_sched_barrier(0);

    // ---- phase 2: C2 = inner @ oc^T + tv
    f32x4 acc2[4];
#pragma unroll
    for (int nt = 0; nt < 4; ++nt)
#pragma unroll
        for (int r = 0; r < 4; ++r) acc2[nt][r] = 0.f;
    KLOOP(acc2, Wp2)

    float tv2[4][4];
#pragma unroll
    for (int nt = 0; nt < 4; ++nt)
#pragma unroll
        for (int r = 0; r < 4; ++r) tv2[nt][r] = acc2[nt][r] + tv[nt][r];

    float mu3[4], rs3[4];
    ROWSTATS(tv2, mu3, rs3)

    float yv[4][4];
#pragma unroll
    for (int nt = 0; nt < 4; ++nt) {
        int n = wave * 64 + nt * 16 + l15;
#pragma unroll
        for (int r = 0; r < 4; ++r) {
            float v = (tv2[nt][r] - mu3[r]) * rs3[r] * g.w3[n] + g.b3[n];
            yv[nt][r] = v;
            if (LAST) g.outp[(size_t)(m0 + quad * 4 + r) * D_ + n] = v;
            else      g.srcf[(size_t)(m0 + quad * 4 + r) * D_ + n] = v;
        }
    }

    if (!LAST) {
        float mu1[4], rs1[4];
        ROWSTATS(yv, mu1, rs1)
#pragma unroll
        for (int nt = 0; nt < 4; ++nt) {
            int n = wave * 64 + nt * 16 + l15;
#pragma unroll
            for (int r = 0; r < 4; ++r)
                g.zb[(size_t)(m0 + quad * 4 + r) * D_ + n] =
                    f2us((yv[nt][r] - mu1[r]) * rs1[r] * g.w1n[n] + g.b1n[n]);
        }
    }
    #undef KLOOP
    #undef ROWSTATS
}

// ---------- MFMA flash attention, SWAPPED QK^T, packed P-writes ----------
__global__ __launch_bounds__(256) void attn_k(const unsigned short* __restrict__ Q,
                                              const unsigned short* __restrict__ K,
                                              const unsigned short* __restrict__ vt,
                                              const unsigned short* __restrict__ R,
                                              const int* __restrict__ mask,
                                              unsigned short* __restrict__ O) {
    __shared__ unsigned short Ks[2][64 * 64];
    __shared__ unsigned short Vts[2][64 * 64];
    __shared__ unsigned short Ps[4][16][72];
    __shared__ float Ms[1024];

    int bh = blockIdx.x;
    int b = bh >> 3, h = bh & 7;
    int qt0 = blockIdx.y * 64;
    int t = threadIdx.x, wave = t >> 6, lane = t & 63;
    int l15 = lane & 15, quad = lane >> 4;
    int qw0 = qt0 + wave * 16;

    const unsigned short* Qrow = Q + ((size_t)(b * S_ + qw0 + l15) * H_ + h) * DH_;
    bf16x8 qf[2];
    qf[0] = *(const bf16x8*)(Qrow + quad * 8);
    qf[1] = *(const bf16x8*)(Qrow + 32 + quad * 8);

#pragma unroll
    for (int u = 0; u < 4; ++u)
        Ms[u * 256 + t] = mask[b * S_ + u * 256 + t] ? 0.f : -1e10f;
    asm volatile("s_waitcnt lgkmcnt(0)" ::: "memory");

    float lsum = 0.f;                    // sum over k for q = l15
    f32x4 acc_o[4];
#pragma unroll
    for (int dt = 0; dt < 4; ++dt)
#pragma unroll
        for (int r = 0; r < 4; ++r) acc_o[dt][r] = 0.f;

    int lro = lane >> 3;
    int cglob = (lane & 7) ^ lro;
    const unsigned short* kgp0 =
        K + ((size_t)(b * S_ + wave * 16 + lro) * H_ + h) * DH_ + cglob * 8;
    const unsigned short* vgp0 =
        vt + (size_t)(b * 512 + h * 64 + wave * 16 + lro) * 1024 + cglob * 8;
    int swz = l15 & 7;
    const float SC = 0.125f * 1.44269504089f;

    #define ASTAGE(buf, kt)                                                         \
        do {                                                                        \
            GLL(kgp0 + (size_t)(kt) * 64 * 512,           &Ks[buf][(wave * 16) * 64]);     \
            GLL(kgp0 + (size_t)(kt) * 64 * 512 + 8 * 512, &Ks[buf][(wave * 16 + 8) * 64]); \
            GLL(vgp0 + (kt) * 64,                         &Vts[buf][(wave * 16) * 64]);    \
            GLL(vgp0 + (kt) * 64 + 8 * 1024,              &Vts[buf][(wave * 16 + 8) * 64]);\
        } while (0)

    ASTAGE(0, 0);

    int cur = 0;
    for (int kt = 0; kt < 16; ++kt) {
        if (kt < 15) {
            ASTAGE(cur ^ 1, kt + 1);
            asm volatile("s_waitcnt vmcnt(4)" ::: "memory");
        } else {
            asm volatile("s_waitcnt vmcnt(0)" ::: "memory");
        }
        __builtin_amdgcn_s_barrier();
        __builtin_amdgcn_sched_barrier(0);

        // S^T = K @ Q^T
        f32x4 accs[4];
#pragma unroll
        for (int jt = 0; jt < 4; ++jt)
#pragma unroll
            for (int r = 0; r < 4; ++r) accs[jt][r] = 0.f;
        __builtin_amdgcn_s_setprio(1);
#pragma unroll
        for (int kc = 0; kc < 2; ++kc) {
            int ch = ((kc * 4 + quad) ^ swz) * 8;
#pragma unroll
            for (int jt = 0; jt < 4; ++jt) {
                bf16x8 kf = *(const bf16x8*)&Ks[cur][(jt * 16 + l15) * 64 + ch];
                accs[jt] = __builtin_amdgcn_mfma_f32_16x16x32_bf16(kf, qf[kc], accs[jt], 0, 0, 0);
            }
        }
        __builtin_amdgcn_s_setprio(0);

        // softmax-lite; pack 4 bf16 -> one b64 write per jt
#pragma unroll
        for (int jt = 0; jt < 4; ++jt) {
            int kb = kt * 64 + jt * 16 + quad * 4;
            float p0 = __builtin_amdgcn_exp2f(accs[jt][0] * SC + Ms[kb + 0]);
            float p1 = __builtin_amdgcn_exp2f(accs[jt][1] * SC + Ms[kb + 1]);
            float p2 = __builtin_amdgcn_exp2f(accs[jt][2] * SC + Ms[kb + 2]);
            float p3 = __builtin_amdgcn_exp2f(accs[jt][3] * SC + Ms[kb + 3]);
            lsum += (p0 + p1) + (p2 + p3);
            uint2 pk;
            pk.x = __builtin_amdgcn_perm(__float_as_uint(p1), __float_as_uint(p0), 0x07060302u);
            pk.y = __builtin_amdgcn_perm(__float_as_uint(p3), __float_as_uint(p2), 0x07060302u);
            *(uint2*)&Ps[wave][l15][jt * 16 + quad * 4] = pk;
        }

        // O += P @ V
        __builtin_amdgcn_s_setprio(1);
#pragma unroll
        for (int kc = 0; kc < 2; ++kc) {
            bf16x8 pf = *(const bf16x8*)&Ps[wave][l15][kc * 32 + quad * 8];
            int ch = ((kc * 4 + quad) ^ swz) * 8;
#pragma unroll
            for (int dt = 0; dt < 4; ++dt) {
                bf16x8 vf = *(const bf16x8*)&Vts[cur][(dt * 16 + l15) * 64 + ch];
                acc_o[dt] = __builtin_amdgcn_mfma_f32_16x16x32_bf16(pf, vf, acc_o[dt], 0, 0, 0);
            }
        }
        __builtin_amdgcn_s_setprio(0);

        __builtin_amdgcn_sched_barrier(0);
        __builtin_amdgcn_s_barrier();
        cur ^= 1;
    }
    #undef ASTAGE

    lsum += __shfl_xor(lsum, 16);
    lsum += __shfl_xor(lsum, 32);

#pragma unroll
    for (int r = 0; r < 4; ++r) {
        int qq = quad * 4 + r;
        int q = qw0 + qq;
        float inv = 1.f / __shfl(lsum, qq);
        const unsigned short* Rr = R + ((size_t)(b * S_ + q) * H_ + h) * DH_;
        unsigned short* Or = O + ((size_t)(b * S_ + q) * H_ + h) * DH_;
#pragma unroll
        for (int dt = 0; dt < 4; ++dt) {
            int d = dt * 16 + l15;
            Or[d] = f2us(acc_o[dt][r] * inv * us2f(Rr[d]));
        }
    }
}

extern "C" void kernel_launch(void* const* d_in, const int* in_sizes, int n_in,
                              void* d_out, int out_size, void* d_ws, size_t ws_size,
                              hipStream_t stream) {
    const float* src  = (const float*)d_in[0];
    const float* ln1w = (const float*)d_in[1];
    const float* ln1b = (const float*)d_in[2];
    const float* ln2w = (const float*)d_in[3];
    const float* ln2b = (const float*)d_in[4];
    const float* ln3w = (const float*)d_in[5];
    const float* ln3b = (const float*)d_in[6];
    const float* wq   = (const float*)d_in[7];
    const float* wqb  = (const float*)d_in[8];
    const float* wk   = (const float*)d_in[9];
    const float* wkb  = (const float*)d_in[10];
    const float* wv   = (const float*)d_in[11];
    const float* wvb  = (const float*)d_in[12];
    const float* wr   = (const float*)d_in[13];
    const float* wrb  = (const float*)d_in[14];
    const float* wo   = (const float*)d_in[15];
    const float* wob  = (const float*)d_in[16];
    const float* ic   = (const float*)d_in[17];
    const float* oc   = (const float*)d_in[18];
    const int* mask   = (const int*)d_in[19];
    float* out = (float*)d_out;

    // ws: srcf 8MB | zb 4 | q 4 | k 4 | v 4 | r 4 | cw24 12  = 40MB
    float* srcf = (float*)d_ws;
    unsigned short* zb = (unsigned short*)(srcf + NT);
    unsigned short* qb = zb + NT;
    unsigned short* kb = qb + NT;
    unsigned short* vb = kb + NT;   // V transposed: vt[(b*512+h*64+d)*1024+s]
    unsigned short* rb = vb + NT;
    unsigned short* cw = rb + NT;   // 24 matrices: (l*6 + {q,k,v,r,o,oc}) * DD

    PreArgs pa;
    pa.w[0] = wq; pa.w[1] = wk; pa.w[2] = wv;
    pa.w[3] = wr; pa.w[4] = wo; pa.w[5] = oc;
    pa.cw = cw; pa.src = src; pa.ln1w = ln1w; pa.ln1b = ln1b;
    pa.srcf = srcf; pa.z = zb;
    pre_k<<<dim3(6144 + NTOK / 4), dim3(256), 0, stream>>>(pa);

    for (int l = 0; l < L_; ++l) {
        unsigned short* cwl = cw + (size_t)l * 6 * DD;

        MGemm128Args ga;
        ga.A = zb;
        ga.W[0] = cwl + 0 * DD; ga.bias[0] = wqb + l * D_; ga.C[0] = qb; ga.tflag[0] = 0;
        ga.W[1] = cwl + 1 * DD; ga.bias[1] = wkb + l * D_; ga.C[1] = kb; ga.tflag[1] = 0;
        ga.W[2] = cwl + 2 * DD; ga.bias[2] = wvb + l * D_; ga.C[2] = vb; ga.tflag[2] = 1;
        ga.W[3] = cwl + 3 * DD; ga.bias[3] = wrb + l * D_; ga.C[3] = rb; ga.tflag[3] = 0;
        mgemm128_k<<<dim3(4, 32, 4), dim3(256), 0, stream>>>(ga);

        attn_k<<<dim3(32, 16), dim3(256), 0, stream>>>(qb, kb, vb, rb, mask, zb);

        GFArgs gf;
        gf.A = zb; gf.W1 = cwl + 4 * DD; gf.W2 = cwl + 5 * DD;
        gf.bias1 = wob + l * D_; gf.res = srcf;
        gf.srcf = srcf; gf.outp = out; gf.zb = zb;
        gf.w2a = ln2w + l * D_; gf.b2a = ln2b + l * D_;
        gf.w3 = ln3w + l * D_; gf.b3 = ln3b + l * D_;
        gf.w1n = (l < L_ - 1) ? ln1w + (l + 1) * D_ : nullptr;
        gf.b1n = (l < L_ - 1) ? ln1b + (l + 1) * D_ : nullptr;
        gf.ic = ic + (size_t)l * D_ * 5;

        if (l < L_ - 1)
            gemmfused_k<0><<<dim3(NTOK / 16), dim3(512), 0, stream>>>(gf);
        else
            gemmfused_k<1><<<dim3(NTOK / 16), dim3(512), 0, stream>>>(gf);
    }
}

// Round 14
// 350.224 us; speedup vs baseline: 1.0958x; 1.0203x over previous
//
#include <hip/hip_runtime.h>

// Established: all float inputs fp32, output fp32, mask int32. ws >= 256MB.
#define B_   4
#define S_   1024
#define D_   512
#define H_   8
#define DH_  64
#define L_   4
#define NTOK (B_ * S_)            // 4096 tokens
#define NT   (NTOK * D_)          // 2097152 elems per activation
#define DD   (D_ * D_)            // 262144 elems per weight matrix

typedef __attribute__((ext_vector_type(8))) short bf16x8;
typedef __attribute__((ext_vector_type(4))) float f32x4;

// async global->LDS, 16B per lane; LDS dest = wave-uniform base + lane*16
#define GLL(gp, lp)                                                            \
    __builtin_amdgcn_global_load_lds(                                          \
        (const __attribute__((address_space(1))) unsigned int*)(gp),           \
        (__attribute__((address_space(3))) unsigned int*)(lp), 16, 0, 0)

// ---------- bf16 helpers ----------
__device__ __forceinline__ float us2f(unsigned short u) {
    unsigned int v = ((unsigned int)u) << 16;
    return __uint_as_float(v);
}
__device__ __forceinline__ unsigned short f2us(float f) {
    unsigned int u = __float_as_uint(f);
    unsigned int r = (u + 0x7fffu + ((u >> 16) & 1u)) >> 16;
    return (unsigned short)r;
}

// fast tanh: 1 - 2/(exp2(2*log2e*z)+1); clamp avoids inf/inf. err ~1e-7.
__device__ __forceinline__ float tanh_fast(float z) {
    float zc = fminf(fmaxf(z, -20.f), 20.f);
    float e = __builtin_amdgcn_exp2f(zc * 2.8853900817779268f);
    return 1.f - 2.f * __builtin_amdgcn_rcpf(e + 1.f);
}

// standard uniform cubic B-spline M(t), support [-2,2]:
// M(t) = ((2-|t|)^3 - 4*max(1-|t|,0)^3) / 6
__device__ __forceinline__ float bspl3(float u) {
    float a = fabsf(u);
    float t2 = fmaxf(2.f - a, 0.f);
    float t1 = fmaxf(1.f - a, 0.f);
    float c2 = t2 * t2 * t2;
    float c1 = t1 * t1 * t1;
    return (c2 - 4.f * c1) * (1.f / 6.f);
}

// KAN inner on uniform knots h=2/7: B3[0] = M((xt+3/7)*3.5), B3[1] = M((xt+1/7)*3.5).
__device__ __forceinline__ float kan_fast(float zv, float c0, float c1) {
    float xt = tanh_fast(zv);
    float b0 = bspl3(__builtin_fmaf(xt, 3.5f, 1.5f));
    float b1 = bspl3(__builtin_fmaf(xt, 3.5f, 0.5f));
    return c0 * b0 + c1 * b1;
}

// ---------- merged upfront kernel: weight conversion + src copy + first LN1 ----------
struct PreArgs {
    const float* w[6];            // layer-0 base ptrs of the 6 weight tensors
    unsigned short* cw;           // 24*DD bf16 out
    const float* src;
    const float* ln1w;
    const float* ln1b;
    float* srcf;
    unsigned short* z;
};
__global__ __launch_bounds__(256) void pre_k(PreArgs a) {
    int bx = blockIdx.x;
    if (bx < 6144) {
        int y = bx >> 8;                     // matrix index 0..23 (= l*6 + t)
        int l = y / 6, tp = y - l * 6;
        int i = ((bx & 255) * 256 + threadIdx.x) * 4;
        float4 v = *(const float4*)(a.w[tp] + (size_t)l * DD + i);
        ushort4 o;
        o.x = f2us(v.x); o.y = f2us(v.y); o.z = f2us(v.z); o.w = f2us(v.w);
        *(ushort4*)(a.cw + (size_t)y * DD + i) = o;
    } else {
        int wv = threadIdx.x >> 6, lane = threadIdx.x & 63;
        int tok = (bx - 6144) * 4 + wv;
        const float* xr = a.src + (size_t)tok * D_;
        float v[8];
        float s = 0.f, s2 = 0.f;
#pragma unroll
        for (int i = 0; i < 8; ++i) {
            float t = xr[lane + 64 * i];
            v[i] = t; s += t; s2 += t * t;
        }
#pragma unroll
        for (int o = 1; o < 64; o <<= 1) { s += __shfl_xor(s, o); s2 += __shfl_xor(s2, o); }
        float mu = s * (1.f / D_);
        float var = s2 * (1.f / D_) - mu * mu;
        float rs = rsqrtf(var + 1e-5f);
#pragma unroll
        for (int i = 0; i < 8; ++i) {
            int d = lane + 64 * i;
            a.srcf[(size_t)tok * D_ + d] = v[i];
            a.z[(size_t)tok * D_ + d] = f2us((v[i] - mu) * rs * a.ln1w[d] + a.ln1b[d]);
        }
    }
}

// ---------- MFMA GEMM A: 128x128 tile, BK=64, dbuf 2-phase, COUNTED vmcnt ----------
struct MGemm128Args {
    const unsigned short* A;
    const unsigned short* W[4];
    const float* bias[4];
    unsigned short* C[4];
    int tflag[4];
};

__global__ __launch_bounds__(256) void mgemm128_k(MGemm128Args g) {
    __shared__ unsigned short As[2][128 * 64];
    __shared__ unsigned short Bs[2][128 * 64];
    int id = blockIdx.x + (blockIdx.y << 2) + (blockIdx.z << 7);   // 0..511
    int id2 = ((id & 7) << 6) + (id >> 3);                         // bijective (512 = 8*64)
    int z = id2 >> 7;
    const unsigned short* W = g.W[z];
    const float* bias = g.bias[z];
    unsigned short* C = g.C[z];
    int m0 = ((id2 >> 2) & 31) * 128, n0 = (id2 & 3) * 128;
    int t = threadIdx.x;
    int wave = t >> 6, lane = t & 63;
    int wm = (wave >> 1) * 64, wn = (wave & 1) * 64;
    int l15 = lane & 15, quad = lane >> 4;
    int srow = lane >> 3, schunk = lane & 7;    // staging: 8 rows x 8 chunks per GLL

    f32x4 acc[4][4];
#pragma unroll
    for (int i = 0; i < 4; ++i)
#pragma unroll
        for (int j = 0; j < 4; ++j)
#pragma unroll
            for (int r = 0; r < 4; ++r) acc[i][j][r] = 0.f;

    int rb = wave * 32;                          // each wave stages 32 rows of A and B
    int swz = l15 & 7;

    #define STAGE128(buf, k0)                                                       \
        do {                                                                        \
            _Pragma("unroll")                                                       \
            for (int g8 = 0; g8 < 4; ++g8) {                                        \
                int row0 = rb + g8 * 8;                                             \
                int row = row0 + srow;                                              \
                int cg = schunk ^ (row & 7);                                        \
                GLL(g.A + (size_t)(m0 + row) * D_ + (k0) + cg * 8, &As[buf][row0 * 64]); \
                GLL(W   + (size_t)(n0 + row) * D_ + (k0) + cg * 8, &Bs[buf][row0 * 64]); \
            }                                                                       \
        } while (0)

    STAGE128(0, 0);

    int cur = 0;
    for (int ks = 0; ks < 8; ++ks) {
        if (ks < 7) {
            STAGE128(cur ^ 1, (ks + 1) * 64);
            asm volatile("s_waitcnt vmcnt(8)" ::: "memory");   // tile ks landed; prefetch in flight
        } else {
            asm volatile("s_waitcnt vmcnt(0)" ::: "memory");
        }
        __builtin_amdgcn_s_barrier();
        __builtin_amdgcn_sched_barrier(0);
#pragma unroll
        for (int kc = 0; kc < 2; ++kc) {
            int ch = ((kc * 4 + quad) ^ swz) * 8;
            bf16x8 af[4], bfr[4];
#pragma unroll
            for (int mt = 0; mt < 4; ++mt)
                af[mt] = *(const bf16x8*)&As[cur][(wm + mt * 16 + l15) * 64 + ch];
#pragma unroll
            for (int nt = 0; nt < 4; ++nt)
                bfr[nt] = *(const bf16x8*)&Bs[cur][(wn + nt * 16 + l15) * 64 + ch];
#pragma unroll
            for (int mt = 0; mt < 4; ++mt)
#pragma unroll
                for (int nt = 0; nt < 4; ++nt)
                    acc[mt][nt] = __builtin_amdgcn_mfma_f32_16x16x32_bf16(
                        af[mt], bfr[nt], acc[mt][nt], 0, 0, 0);
        }
        __builtin_amdgcn_sched_barrier(0);
        __builtin_amdgcn_s_barrier();
        cur ^= 1;
    }
    #undef STAGE128

    if (g.tflag[z]) {
#pragma unroll
        for (int mt = 0; mt < 4; ++mt)
#pragma unroll
            for (int nt = 0; nt < 4; ++nt) {
                int n = n0 + wn + nt * 16 + l15;
                float bv = bias[n];
                int m = m0 + wm + mt * 16 + quad * 4;
                ushort4 pk;
                pk.x = f2us(acc[mt][nt][0] + bv);
                pk.y = f2us(acc[mt][nt][1] + bv);
                pk.z = f2us(acc[mt][nt][2] + bv);
                pk.w = f2us(acc[mt][nt][3] + bv);
                *(ushort4*)(C + ((size_t)(m >> 10) * 512 + n) * 1024 + (m & 1023)) = pk;
            }
    } else {
#pragma unroll
        for (int mt = 0; mt < 4; ++mt)
#pragma unroll
            for (int nt = 0; nt < 4; ++nt) {
                int n = n0 + wn + nt * 16 + l15;
                float bv = bias[n];
#pragma unroll
                for (int r = 0; r < 4; ++r) {
                    int m = m0 + wm + mt * 16 + quad * 4 + r;
                    C[(size_t)m * D_ + n] = f2us(acc[mt][nt][r] + bv);
                }
            }
    }
}

// ---------- FUSED double-GEMM block: Wo-GEMM + LN2 + KAN + oc-GEMM + LN3(+LN1) ----
struct GFArgs {
    const unsigned short* A;      // zb (attn out, bf16)
    const unsigned short* W1;     // Wo (bf16)
    const unsigned short* W2;     // oc (bf16)
    const float* bias1;           // Wo bias
    const float* res;             // srcf (residual in)
    float* srcf;                  // residual out (LN3'd) [!LAST]
    float* outp;                  // final out [LAST]
    unsigned short* zb;           // LN1 out (next layer) [!LAST]
    const float* w2a; const float* b2a;   // LN2
    const float* w3;  const float* b3;    // LN3
    const float* w1n; const float* b1n;   // LN1 (next layer)
    const float* ic;              // inner_c
};

template <int LAST>
__global__ __launch_bounds__(512) void gemmfused_k(GFArgs g) {
    __shared__ unsigned short Bs[2][512 * 64];   // 128 KB, per-wave 64-row panels
    __shared__ unsigned short Asm[16 * 512];     // 16 KB: phase1 A, then KAN inner
    __shared__ float redS[16][8];
    __shared__ float redS2[16][8];

    int m0 = blockIdx.x * 16;
    int t = threadIdx.x, wave = t >> 6, lane = t & 63;
    int l15 = lane & 15, quad = lane >> 4;
    int srow = lane >> 3, schunk = lane & 7;
    int swz = l15 & 7;

    // ---- prologue: A rows (2/wave, full K, chunk-XOR swizzled) + W1 tiles 0,1
#pragma unroll
    for (int rr = 0; rr < 2; ++rr) {
        int r = wave * 2 + rr;
        GLL(g.A + (size_t)(m0 + r) * D_ + (lane ^ (r & 7)) * 8, &Asm[r * 512]);
    }
    const unsigned short* Wp1 = g.W1 + (size_t)(wave * 64 + srow) * D_ + (schunk ^ srow) * 8;
#pragma unroll
    for (int g8 = 0; g8 < 8; ++g8)
        GLL(Wp1 + (size_t)g8 * 8 * D_, &Bs[0][(wave * 64 + g8 * 8) * 64]);
#pragma unroll
    for (int g8 = 0; g8 < 8; ++g8)
        GLL(Wp1 + 64 + (size_t)g8 * 8 * D_, &Bs[1][(wave * 64 + g8 * 8) * 64]);
    asm volatile("s_waitcnt vmcnt(16)" ::: "memory");   // A landed (oldest 2)
    __builtin_amdgcn_s_barrier();                        // Asm visible to all waves

    // per-wave 2-deep pipelined k-loop (8 steps of BK=64)
    #define KLOOP(accv, Wp)                                                           \
        for (int ks = 0; ks < 8; ++ks) {                                              \
            if (ks < 7) asm volatile("s_waitcnt vmcnt(8)" ::: "memory");              \
            else        asm volatile("s_waitcnt vmcnt(0)" ::: "memory");              \
            __builtin_amdgcn_sched_barrier(0);                                        \
            _Pragma("unroll")                                                         \
            for (int kc = 0; kc < 2; ++kc) {                                          \
                bf16x8 af = *(const bf16x8*)&Asm[l15 * 512 +                          \
                                                 ((ks * 8 + kc * 4 + quad) ^ swz) * 8];\
                _Pragma("unroll")                                                     \
                for (int nt = 0; nt < 4; ++nt) {                                      \
                    bf16x8 bf = *(const bf16x8*)&Bs[ks & 1][(wave * 64 + nt * 16 + l15) * 64 + \
                                                            ((kc * 4 + quad) ^ swz) * 8];      \
                    accv[nt] = __builtin_amdgcn_mfma_f32_16x16x32_bf16(af, bf, accv[nt], 0, 0, 0); \
                }                                                                     \
            }                                                                         \
            __builtin_amdgcn_sched_barrier(0);                                        \
            if (ks < 6) {                                                             \
                _Pragma("unroll")                                                     \
                for (int g8 = 0; g8 < 8; ++g8)                                        \
                    GLL(Wp + (ks + 2) * 64 + (size_t)g8 * 8 * D_,                     \
                        &Bs[ks & 1][(wave * 64 + g8 * 8) * 64]);                      \
            }                                                                         \
        }

    // row stats over vals[4][4] -> muv[4], rsv[4]
    #define ROWSTATS(vals, muv, rsv)                                                  \
        {                                                                             \
            __builtin_amdgcn_s_barrier();                                             \
            float s_[4] = {0.f, 0.f, 0.f, 0.f}, s2_[4] = {0.f, 0.f, 0.f, 0.f};        \
            _Pragma("unroll")                                                         \
            for (int nt = 0; nt < 4; ++nt)                                            \
                _Pragma("unroll")                                                     \
                for (int r = 0; r < 4; ++r) {                                         \
                    s_[r] += vals[nt][r]; s2_[r] += vals[nt][r] * vals[nt][r];        \
                }                                                                     \
            _Pragma("unroll")                                                         \
            for (int off = 1; off < 16; off <<= 1)                                    \
                _Pragma("unroll")                                                     \
                for (int r = 0; r < 4; ++r) {                                         \
                    s_[r] += __shfl_xor(s_[r], off); s2_[r] += __shfl_xor(s2_[r], off); \
                }                                                                     \
            if (l15 == 0) {                                                           \
                _Pragma("unroll")                                                     \
                for (int r = 0; r < 4; ++r) {                                         \
                    redS[quad * 4 + r][wave] = s_[r]; redS2[quad * 4 + r][wave] = s2_[r]; \
                }                                                                     \
            }                                                                         \
            asm volatile("s_waitcnt lgkmcnt(0)" ::: "memory");                        \
            __builtin_amdgcn_s_barrier();                                             \
            _Pragma("unroll")                                                         \
            for (int r = 0; r < 4; ++r) {                                             \
                float ss = 0.f, ss2 = 0.f;                                            \
                _Pragma("unroll")                                                     \
                for (int w = 0; w < 8; ++w) {                                         \
                    ss += redS[quad * 4 + r][w]; ss2 += redS2[quad * 4 + r][w];       \
                }                                                                     \
                muv[r] = ss * (1.f / D_);                                             \
                rsv[r] = rsqrtf(ss2 * (1.f / D_) - muv[r] * muv[r] + 1e-5f);          \
            }                                                                         \
        }

    // ---- phase 1: C1 = A @ Wo^T
    f32x4 acc[4];
#pragma unroll
    for (int nt = 0; nt < 4; ++nt)
#pragma unroll
        for (int r = 0; r < 4; ++r) acc[nt][r] = 0.f;
    KLOOP(acc, Wp1)

    // ---- issue phase-2 W staging NOW (hides under epilogue; Bs per-wave free)
    const unsigned short* Wp2 = g.W2 + (size_t)(wave * 64 + srow) * D_ + (schunk ^ srow) * 8;
#pragma unroll
    for (int g8 = 0; g8 < 8; ++g8)
        GLL(Wp2 + (size_t)g8 * 8 * D_, &Bs[0][(wave * 64 + g8 * 8) * 64]);
#pragma unroll
    for (int g8 = 0; g8 < 8; ++g8)
        GLL(Wp2 + 64 + (size_t)g8 * 8 * D_, &Bs[1][(wave * 64 + g8 * 8) * 64]);

    // hoist LN2 params + KAN coeffs per nt (latency hides under ROWSTATS)
    float c0v[4], c1v[4], w2v[4], b2v[4];
#pragma unroll
    for (int nt = 0; nt < 4; ++nt) {
        int n = wave * 64 + nt * 16 + l15;
        c0v[nt] = g.ic[n * 5 + 0];
        c1v[nt] = g.ic[n * 5 + 1];
        w2v[nt] = g.w2a[n];
        b2v[nt] = g.b2a[n];
    }

    // ---- epilogue 1: tv = acc + bias + res (regs only)
    float tv[4][4];
#pragma unroll
    for (int nt = 0; nt < 4; ++nt) {
        int n = wave * 64 + nt * 16 + l15;
        float bv = g.bias1[n];
#pragma unroll
        for (int r = 0; r < 4; ++r)
            tv[nt][r] = acc[nt][r] + bv + g.res[(size_t)(m0 + quad * 4 + r) * D_ + n];
    }

    float mu2[4], rs2[4];
    ROWSTATS(tv, mu2, rs2)

    // ---- KAN inner (closed-form uniform B-spline) -> Asm LDS (swizzled)
#pragma unroll
    for (int nt = 0; nt < 4; ++nt) {
        int n = wave * 64 + nt * 16 + l15;
        int gch = n >> 3;                      // global k-chunk
#pragma unroll
        for (int r = 0; r < 4; ++r) {
            int row = quad * 4 + r;
            float zv = (tv[nt][r] - mu2[r]) * rs2[r] * w2v[nt] + b2v[nt];
            Asm[row * 512 + (gch ^ (row & 7)) * 8 + (n & 7)] =
                f2us(kan_fast(zv, c0v[nt], c1v[nt]));
        }
    }
    asm volatile("s_waitcnt lgkmcnt(0)" ::: "memory");
    __builtin_amdgcn_s_barrier();              // inner visible to all waves
    __builtin_amdgcn_sched_barrier(0);

    // ---- phase 2: C2 = inner @ oc^T + tv
    f32x4 acc2[4];
#pragma unroll
    for (int nt = 0; nt < 4; ++nt)
#pragma unroll
        for (int r = 0; r < 4; ++r) acc2[nt][r] = 0.f;
    KLOOP(acc2, Wp2)

    float tv2[4][4];
#pragma unroll
    for (int nt = 0; nt < 4; ++nt)
#pragma unroll
        for (int r = 0; r < 4; ++r) tv2[nt][r] = acc2[nt][r] + tv[nt][r];

    float mu3[4], rs3[4];
    ROWSTATS(tv2, mu3, rs3)

    float yv[4][4];
#pragma unroll
    for (int nt = 0; nt < 4; ++nt) {
        int n = wave * 64 + nt * 16 + l15;
#pragma unroll
        for (int r = 0; r < 4; ++r) {
            float v = (tv2[nt][r] - mu3[r]) * rs3[r] * g.w3[n] + g.b3[n];
            yv[nt][r] = v;
            if (LAST) g.outp[(size_t)(m0 + quad * 4 + r) * D_ + n] = v;
            else      g.srcf[(size_t)(m0 + quad * 4 + r) * D_ + n] = v;
        }
    }

    if (!LAST) {
        float mu1[4], rs1[4];
        ROWSTATS(yv, mu1, rs1)
#pragma unroll
        for (int nt = 0; nt < 4; ++nt) {
            int n = wave * 64 + nt * 16 + l15;
#pragma unroll
            for (int r = 0; r < 4; ++r)
                g.zb[(size_t)(m0 + quad * 4 + r) * D_ + n] =
                    f2us((yv[nt][r] - mu1[r]) * rs1[r] * g.w1n[n] + g.b1n[n]);
        }
    }
    #undef KLOOP
    #undef ROWSTATS
}

// ---------- MFMA flash attention, SWAPPED QK^T, packed P-writes, PAIR-UNROLLED ----
// 4 LDS buffers, kv-tiles processed in pairs: barriers 32->16, counted-vmcnt
// waits 16->8, 2x compute per synchronization region. Staging targets the pair
// consumed at ktp-1, separated from its last reads by that pair's exit barrier
// (same hazard discipline as the 1-tile scheme). vmcnt ledger: 8 outstanding
// carried, +8 staged, wait(8) drains exactly the current pair.
__global__ __launch_bounds__(256) void attn_k(const unsigned short* __restrict__ Q,
                                              const unsigned short* __restrict__ K,
                                              const unsigned short* __restrict__ vt,
                                              const unsigned short* __restrict__ R,
                                              const int* __restrict__ mask,
                                              unsigned short* __restrict__ O) {
    __shared__ unsigned short Ks[4][64 * 64];    // 32 KB
    __shared__ unsigned short Vts[4][64 * 64];   // 32 KB
    __shared__ unsigned short Ps[4][16][72];
    __shared__ float Ms[1024];

    int bh = blockIdx.x;
    int b = bh >> 3, h = bh & 7;
    int qt0 = blockIdx.y * 64;
    int t = threadIdx.x, wave = t >> 6, lane = t & 63;
    int l15 = lane & 15, quad = lane >> 4;
    int qw0 = qt0 + wave * 16;

    const unsigned short* Qrow = Q + ((size_t)(b * S_ + qw0 + l15) * H_ + h) * DH_;
    bf16x8 qf[2];
    qf[0] = *(const bf16x8*)(Qrow + quad * 8);
    qf[1] = *(const bf16x8*)(Qrow + 32 + quad * 8);

#pragma unroll
    for (int u = 0; u < 4; ++u)
        Ms[u * 256 + t] = mask[b * S_ + u * 256 + t] ? 0.f : -1e10f;
    asm volatile("s_waitcnt lgkmcnt(0)" ::: "memory");

    float lsum = 0.f;                    // sum over k for q = l15
    f32x4 acc_o[4];
#pragma unroll
    for (int dt = 0; dt < 4; ++dt)
#pragma unroll
        for (int r = 0; r < 4; ++r) acc_o[dt][r] = 0.f;

    int lro = lane >> 3;
    int cglob = (lane & 7) ^ lro;
    const unsigned short* kgp0 =
        K + ((size_t)(b * S_ + wave * 16 + lro) * H_ + h) * DH_ + cglob * 8;
    const unsigned short* vgp0 =
        vt + (size_t)(b * 512 + h * 64 + wave * 16 + lro) * 1024 + cglob * 8;
    int swz = l15 & 7;
    const float SC = 0.125f * 1.44269504089f;

    #define ASTAGE(buf, kt)                                                         \
        do {                                                                        \
            GLL(kgp0 + (size_t)(kt) * 64 * 512,           &Ks[buf][(wave * 16) * 64]);     \
            GLL(kgp0 + (size_t)(kt) * 64 * 512 + 8 * 512, &Ks[buf][(wave * 16 + 8) * 64]); \
            GLL(vgp0 + (kt) * 64,                         &Vts[buf][(wave * 16) * 64]);    \
            GLL(vgp0 + (kt) * 64 + 8 * 1024,              &Vts[buf][(wave * 16 + 8) * 64]);\
        } while (0)

    ASTAGE(0, 0);
    ASTAGE(1, 1);

    for (int ktp = 0; ktp < 8; ++ktp) {
        int kt = ktp * 2;
        int b0 = (ktp & 1) * 2;        // buffers holding this pair
        if (ktp < 7) {
            ASTAGE(b0 ^ 2, kt + 2);    // stage next pair into the pair consumed at ktp-1
            ASTAGE((b0 ^ 2) + 1, kt + 3);
            asm volatile("s_waitcnt vmcnt(8)" ::: "memory");   // current pair landed
        } else {
            asm volatile("s_waitcnt vmcnt(0)" ::: "memory");
        }
        __builtin_amdgcn_s_barrier();
        __builtin_amdgcn_sched_barrier(0);

#pragma unroll
        for (int u = 0; u < 2; ++u) {
            int ktc = kt + u;
            int bu = b0 + u;

            // S^T = K @ Q^T
            f32x4 accs[4];
#pragma unroll
            for (int jt = 0; jt < 4; ++jt)
#pragma unroll
                for (int r = 0; r < 4; ++r) accs[jt][r] = 0.f;
            __builtin_amdgcn_s_setprio(1);
#pragma unroll
            for (int kc = 0; kc < 2; ++kc) {
                int ch = ((kc * 4 + quad) ^ swz) * 8;
#pragma unroll
                for (int jt = 0; jt < 4; ++jt) {
                    bf16x8 kf = *(const bf16x8*)&Ks[bu][(jt * 16 + l15) * 64 + ch];
                    accs[jt] = __builtin_amdgcn_mfma_f32_16x16x32_bf16(kf, qf[kc], accs[jt], 0, 0, 0);
                }
            }
            __builtin_amdgcn_s_setprio(0);

            // softmax-lite; pack 4 bf16 -> one b64 write per jt
#pragma unroll
            for (int jt = 0; jt < 4; ++jt) {
                int kb = ktc * 64 + jt * 16 + quad * 4;
                float p0 = __builtin_amdgcn_exp2f(accs[jt][0] * SC + Ms[kb + 0]);
                float p1 = __builtin_amdgcn_exp2f(accs[jt][1] * SC + Ms[kb + 1]);
                float p2 = __builtin_amdgcn_exp2f(accs[jt][2] * SC + Ms[kb + 2]);
                float p3 = __builtin_amdgcn_exp2f(accs[jt][3] * SC + Ms[kb + 3]);
                lsum += (p0 + p1) + (p2 + p3);
                uint2 pk;
                pk.x = __builtin_amdgcn_perm(__float_as_uint(p1), __float_as_uint(p0), 0x07060302u);
                pk.y = __builtin_amdgcn_perm(__float_as_uint(p3), __float_as_uint(p2), 0x07060302u);
                *(uint2*)&Ps[wave][l15][jt * 16 + quad * 4] = pk;
            }

            // O += P @ V
            __builtin_amdgcn_s_setprio(1);
#pragma unroll
            for (int kc = 0; kc < 2; ++kc) {
                bf16x8 pf = *(const bf16x8*)&Ps[wave][l15][kc * 32 + quad * 8];
                int ch = ((kc * 4 + quad) ^ swz) * 8;
#pragma unroll
                for (int dt = 0; dt < 4; ++dt) {
                    bf16x8 vf = *(const bf16x8*)&Vts[bu][(dt * 16 + l15) * 64 + ch];
                    acc_o[dt] = __builtin_amdgcn_mfma_f32_16x16x32_bf16(pf, vf, acc_o[dt], 0, 0, 0);
                }
            }
            __builtin_amdgcn_s_setprio(0);
        }

        __builtin_amdgcn_sched_barrier(0);
        __builtin_amdgcn_s_barrier();
    }
    #undef ASTAGE

    lsum += __shfl_xor(lsum, 16);
    lsum += __shfl_xor(lsum, 32);

#pragma unroll
    for (int r = 0; r < 4; ++r) {
        int qq = quad * 4 + r;
        int q = qw0 + qq;
        float inv = 1.f / __shfl(lsum, qq);
        const unsigned short* Rr = R + ((size_t)(b * S_ + q) * H_ + h) * DH_;
        unsigned short* Or = O + ((size_t)(b * S_ + q) * H_ + h) * DH_;
#pragma unroll
        for (int dt = 0; dt < 4; ++dt) {
            int d = dt * 16 + l15;
            Or[d] = f2us(acc_o[dt][r] * inv * us2f(Rr[d]));
        }
    }
}

extern "C" void kernel_launch(void* const* d_in, const int* in_sizes, int n_in,
                              void* d_out, int out_size, void* d_ws, size_t ws_size,
                              hipStream_t stream) {
    const float* src  = (const float*)d_in[0];
    const float* ln1w = (const float*)d_in[1];
    const float* ln1b = (const float*)d_in[2];
    const float* ln2w = (const float*)d_in[3];
    const float* ln2b = (const float*)d_in[4];
    const float* ln3w = (const float*)d_in[5];
    const float* ln3b = (const float*)d_in[6];
    const float* wq   = (const float*)d_in[7];
    const float* wqb  = (const float*)d_in[8];
    const float* wk   = (const float*)d_in[9];
    const float* wkb  = (const float*)d_in[10];
    const float* wv   = (const float*)d_in[11];
    const float* wvb  = (const float*)d_in[12];
    const float* wr   = (const float*)d_in[13];
    const float* wrb  = (const float*)d_in[14];
    const float* wo   = (const float*)d_in[15];
    const float* wob  = (const float*)d_in[16];
    const float* ic   = (const float*)d_in[17];
    const float* oc   = (const float*)d_in[18];
    const int* mask   = (const int*)d_in[19];
    float* out = (float*)d_out;

    // ws: srcf 8MB | zb 4 | q 4 | k 4 | v 4 | r 4 | cw24 12  = 40MB
    float* srcf = (float*)d_ws;
    unsigned short* zb = (unsigned short*)(srcf + NT);
    unsigned short* qb = zb + NT;
    unsigned short* kb = qb + NT;
    unsigned short* vb = kb + NT;   // V transposed: vt[(b*512+h*64+d)*1024+s]
    unsigned short* rb = vb + NT;
    unsigned short* cw = rb + NT;   // 24 matrices: (l*6 + {q,k,v,r,o,oc}) * DD

    PreArgs pa;
    pa.w[0] = wq; pa.w[1] = wk; pa.w[2] = wv;
    pa.w[3] = wr; pa.w[4] = wo; pa.w[5] = oc;
    pa.cw = cw; pa.src = src; pa.ln1w = ln1w; pa.ln1b = ln1b;
    pa.srcf = srcf; pa.z = zb;
    pre_k<<<dim3(6144 + NTOK / 4), dim3(256), 0, stream>>>(pa);

    for (int l = 0; l < L_; ++l) {
        unsigned short* cwl = cw + (size_t)l * 6 * DD;

        MGemm128Args ga;
        ga.A = zb;
        ga.W[0] = cwl + 0 * DD; ga.bias[0] = wqb + l * D_; ga.C[0] = qb; ga.tflag[0] = 0;
        ga.W[1] = cwl + 1 * DD; ga.bias[1] = wkb + l * D_; ga.C[1] = kb; ga.tflag[1] = 0;
        ga.W[2] = cwl + 2 * DD; ga.bias[2] = wvb + l * D_; ga.C[2] = vb; ga.tflag[2] = 1;
        ga.W[3] = cwl + 3 * DD; ga.bias[3] = wrb + l * D_; ga.C[3] = rb; ga.tflag[3] = 0;
        mgemm128_k<<<dim3(4, 32, 4), dim3(256), 0, stream>>>(ga);

        attn_k<<<dim3(32, 16), dim3(256), 0, stream>>>(qb, kb, vb, rb, mask, zb);

        GFArgs gf;
        gf.A = zb; gf.W1 = cwl + 4 * DD; gf.W2 = cwl + 5 * DD;
        gf.bias1 = wob + l * D_; gf.res = srcf;
        gf.srcf = srcf; gf.outp = out; gf.zb = zb;
        gf.w2a = ln2w + l * D_; gf.b2a = ln2b + l * D_;
        gf.w3 = ln3w + l * D_; gf.b3 = ln3b + l * D_;
        gf.w1n = (l < L_ - 1) ? ln1w + (l + 1) * D_ : nullptr;
        gf.b1n = (l < L_ - 1) ? ln1b + (l + 1) * D_ : nullptr;
        gf.ic = ic + (size_t)l * D_ * 5;

        if (l < L_ - 1)
            gemmfused_k<0><<<dim3(NTOK / 16), dim3(512), 0, stream>>>(gf);
        else
            gemmfused_k<1><<<dim3(NTOK / 16), dim3(512), 0, stream>>>(gf);
    }
}

// Round 15
// 347.320 us; speedup vs baseline: 1.1050x; 1.0084x over previous
//
#include <hip/hip_runtime.h>

// Established: all float inputs fp32, output fp32, mask int32. ws >= 256MB.
#define B_   4
#define S_   1024
#define D_   512
#define H_   8
#define DH_  64
#define L_   4
#define NTOK (B_ * S_)            // 4096 tokens
#define NT   (NTOK * D_)          // 2097152 elems per activation
#define DD   (D_ * D_)            // 262144 elems per weight matrix

typedef __attribute__((ext_vector_type(8))) short bf16x8;
typedef __attribute__((ext_vector_type(4))) float f32x4;

// async global->LDS, 16B per lane; LDS dest = wave-uniform base + lane*16
#define GLL(gp, lp)                                                            \
    __builtin_amdgcn_global_load_lds(                                          \
        (const __attribute__((address_space(1))) unsigned int*)(gp),           \
        (__attribute__((address_space(3))) unsigned int*)(lp), 16, 0, 0)

// ---------- bf16 helpers ----------
__device__ __forceinline__ float us2f(unsigned short u) {
    unsigned int v = ((unsigned int)u) << 16;
    return __uint_as_float(v);
}
__device__ __forceinline__ unsigned short f2us(float f) {
    unsigned int u = __float_as_uint(f);
    unsigned int r = (u + 0x7fffu + ((u >> 16) & 1u)) >> 16;
    return (unsigned short)r;
}

// fast tanh: 1 - 2/(exp2(2*log2e*z)+1); clamp avoids inf/inf. err ~1e-7.
__device__ __forceinline__ float tanh_fast(float z) {
    float zc = fminf(fmaxf(z, -20.f), 20.f);
    float e = __builtin_amdgcn_exp2f(zc * 2.8853900817779268f);
    return 1.f - 2.f * __builtin_amdgcn_rcpf(e + 1.f);
}

// standard uniform cubic B-spline M(t), support [-2,2]:
// M(t) = ((2-|t|)^3 - 4*max(1-|t|,0)^3) / 6
__device__ __forceinline__ float bspl3(float u) {
    float a = fabsf(u);
    float t2 = fmaxf(2.f - a, 0.f);
    float t1 = fmaxf(1.f - a, 0.f);
    float c2 = t2 * t2 * t2;
    float c1 = t1 * t1 * t1;
    return (c2 - 4.f * c1) * (1.f / 6.f);
}

// KAN inner on uniform knots h=2/7: B3[0] = M((xt+3/7)*3.5), B3[1] = M((xt+1/7)*3.5).
__device__ __forceinline__ float kan_fast(float zv, float c0, float c1) {
    float xt = tanh_fast(zv);
    float b0 = bspl3(__builtin_fmaf(xt, 3.5f, 1.5f));
    float b1 = bspl3(__builtin_fmaf(xt, 3.5f, 0.5f));
    return c0 * b0 + c1 * b1;
}

// ---------- merged upfront kernel: weight conversion + src copy + first LN1 ----------
struct PreArgs {
    const float* w[6];            // layer-0 base ptrs of the 6 weight tensors
    unsigned short* cw;           // 24*DD bf16 out
    const float* src;
    const float* ln1w;
    const float* ln1b;
    float* srcf;
    unsigned short* z;
};
__global__ __launch_bounds__(256) void pre_k(PreArgs a) {
    int bx = blockIdx.x;
    if (bx < 6144) {
        int y = bx >> 8;                     // matrix index 0..23 (= l*6 + t)
        int l = y / 6, tp = y - l * 6;
        int i = ((bx & 255) * 256 + threadIdx.x) * 4;
        float4 v = *(const float4*)(a.w[tp] + (size_t)l * DD + i);
        ushort4 o;
        o.x = f2us(v.x); o.y = f2us(v.y); o.z = f2us(v.z); o.w = f2us(v.w);
        *(ushort4*)(a.cw + (size_t)y * DD + i) = o;
    } else {
        int wv = threadIdx.x >> 6, lane = threadIdx.x & 63;
        int tok = (bx - 6144) * 4 + wv;
        const float* xr = a.src + (size_t)tok * D_;
        float v[8];
        float s = 0.f, s2 = 0.f;
#pragma unroll
        for (int i = 0; i < 8; ++i) {
            float t = xr[lane + 64 * i];
            v[i] = t; s += t; s2 += t * t;
        }
#pragma unroll
        for (int o = 1; o < 64; o <<= 1) { s += __shfl_xor(s, o); s2 += __shfl_xor(s2, o); }
        float mu = s * (1.f / D_);
        float var = s2 * (1.f / D_) - mu * mu;
        float rs = rsqrtf(var + 1e-5f);
#pragma unroll
        for (int i = 0; i < 8; ++i) {
            int d = lane + 64 * i;
            a.srcf[(size_t)tok * D_ + d] = v[i];
            a.z[(size_t)tok * D_ + d] = f2us((v[i] - mu) * rs * a.ln1w[d] + a.ln1b[d]);
        }
    }
}

// ---------- MFMA GEMM A: 128x128 tile, BK=64, dbuf 2-phase, COUNTED vmcnt ----------
struct MGemm128Args {
    const unsigned short* A;
    const unsigned short* W[4];
    const float* bias[4];
    unsigned short* C[4];
    int tflag[4];
};

__global__ __launch_bounds__(256) void mgemm128_k(MGemm128Args g) {
    __shared__ unsigned short As[2][128 * 64];
    __shared__ unsigned short Bs[2][128 * 64];
    int id = blockIdx.x + (blockIdx.y << 2) + (blockIdx.z << 7);   // 0..511
    int id2 = ((id & 7) << 6) + (id >> 3);                         // bijective (512 = 8*64)
    int z = id2 >> 7;
    const unsigned short* W = g.W[z];
    const float* bias = g.bias[z];
    unsigned short* C = g.C[z];
    int m0 = ((id2 >> 2) & 31) * 128, n0 = (id2 & 3) * 128;
    int t = threadIdx.x;
    int wave = t >> 6, lane = t & 63;
    int wm = (wave >> 1) * 64, wn = (wave & 1) * 64;
    int l15 = lane & 15, quad = lane >> 4;
    int srow = lane >> 3, schunk = lane & 7;    // staging: 8 rows x 8 chunks per GLL

    f32x4 acc[4][4];
#pragma unroll
    for (int i = 0; i < 4; ++i)
#pragma unroll
        for (int j = 0; j < 4; ++j)
#pragma unroll
            for (int r = 0; r < 4; ++r) acc[i][j][r] = 0.f;

    int rb = wave * 32;                          // each wave stages 32 rows of A and B
    int swz = l15 & 7;

    #define STAGE128(buf, k0)                                                       \
        do {                                                                        \
            _Pragma("unroll")                                                       \
            for (int g8 = 0; g8 < 4; ++g8) {                                        \
                int row0 = rb + g8 * 8;                                             \
                int row = row0 + srow;                                              \
                int cg = schunk ^ (row & 7);                                        \
                GLL(g.A + (size_t)(m0 + row) * D_ + (k0) + cg * 8, &As[buf][row0 * 64]); \
                GLL(W   + (size_t)(n0 + row) * D_ + (k0) + cg * 8, &Bs[buf][row0 * 64]); \
            }                                                                       \
        } while (0)

    STAGE128(0, 0);

    int cur = 0;
    for (int ks = 0; ks < 8; ++ks) {
        if (ks < 7) {
            STAGE128(cur ^ 1, (ks + 1) * 64);
            asm volatile("s_waitcnt vmcnt(8)" ::: "memory");   // tile ks landed; prefetch in flight
        } else {
            asm volatile("s_waitcnt vmcnt(0)" ::: "memory");
        }
        __builtin_amdgcn_s_barrier();
        __builtin_amdgcn_sched_barrier(0);
#pragma unroll
        for (int kc = 0; kc < 2; ++kc) {
            int ch = ((kc * 4 + quad) ^ swz) * 8;
            bf16x8 af[4], bfr[4];
#pragma unroll
            for (int mt = 0; mt < 4; ++mt)
                af[mt] = *(const bf16x8*)&As[cur][(wm + mt * 16 + l15) * 64 + ch];
#pragma unroll
            for (int nt = 0; nt < 4; ++nt)
                bfr[nt] = *(const bf16x8*)&Bs[cur][(wn + nt * 16 + l15) * 64 + ch];
#pragma unroll
            for (int mt = 0; mt < 4; ++mt)
#pragma unroll
                for (int nt = 0; nt < 4; ++nt)
                    acc[mt][nt] = __builtin_amdgcn_mfma_f32_16x16x32_bf16(
                        af[mt], bfr[nt], acc[mt][nt], 0, 0, 0);
        }
        __builtin_amdgcn_sched_barrier(0);
        __builtin_amdgcn_s_barrier();
        cur ^= 1;
    }
    #undef STAGE128

    if (g.tflag[z]) {
#pragma unroll
        for (int mt = 0; mt < 4; ++mt)
#pragma unroll
            for (int nt = 0; nt < 4; ++nt) {
                int n = n0 + wn + nt * 16 + l15;
                float bv = bias[n];
                int m = m0 + wm + mt * 16 + quad * 4;
                ushort4 pk;
                pk.x = f2us(acc[mt][nt][0] + bv);
                pk.y = f2us(acc[mt][nt][1] + bv);
                pk.z = f2us(acc[mt][nt][2] + bv);
                pk.w = f2us(acc[mt][nt][3] + bv);
                *(ushort4*)(C + ((size_t)(m >> 10) * 512 + n) * 1024 + (m & 1023)) = pk;
            }
    } else {
#pragma unroll
        for (int mt = 0; mt < 4; ++mt)
#pragma unroll
            for (int nt = 0; nt < 4; ++nt) {
                int n = n0 + wn + nt * 16 + l15;
                float bv = bias[n];
#pragma unroll
                for (int r = 0; r < 4; ++r) {
                    int m = m0 + wm + mt * 16 + quad * 4 + r;
                    C[(size_t)m * D_ + n] = f2us(acc[mt][nt][r] + bv);
                }
            }
    }
}

// ---------- FUSED double-GEMM block: Wo-GEMM + LN2 + KAN + oc-GEMM + LN3(+LN1) ----
struct GFArgs {
    const unsigned short* A;      // zb (attn out, bf16)
    const unsigned short* W1;     // Wo (bf16)
    const unsigned short* W2;     // oc (bf16)
    const float* bias1;           // Wo bias
    const float* res;             // srcf (residual in)
    float* srcf;                  // residual out (LN3'd) [!LAST]
    float* outp;                  // final out [LAST]
    unsigned short* zb;           // LN1 out (next layer) [!LAST]
    const float* w2a; const float* b2a;   // LN2
    const float* w3;  const float* b3;    // LN3
    const float* w1n; const float* b1n;   // LN1 (next layer)
    const float* ic;              // inner_c
};

template <int LAST>
__global__ __launch_bounds__(512) void gemmfused_k(GFArgs g) {
    __shared__ unsigned short Bs[2][512 * 64];   // 128 KB, per-wave 64-row panels
    __shared__ unsigned short Asm[16 * 512];     // 16 KB: phase1 A, then KAN inner
    __shared__ float redS[16][8];
    __shared__ float redS2[16][8];

    int m0 = blockIdx.x * 16;
    int t = threadIdx.x, wave = t >> 6, lane = t & 63;
    int l15 = lane & 15, quad = lane >> 4;
    int srow = lane >> 3, schunk = lane & 7;
    int swz = l15 & 7;

    // ---- prologue: A rows (2/wave, full K, chunk-XOR swizzled) + W1 tiles 0,1
#pragma unroll
    for (int rr = 0; rr < 2; ++rr) {
        int r = wave * 2 + rr;
        GLL(g.A + (size_t)(m0 + r) * D_ + (lane ^ (r & 7)) * 8, &Asm[r * 512]);
    }
    const unsigned short* Wp1 = g.W1 + (size_t)(wave * 64 + srow) * D_ + (schunk ^ srow) * 8;
#pragma unroll
    for (int g8 = 0; g8 < 8; ++g8)
        GLL(Wp1 + (size_t)g8 * 8 * D_, &Bs[0][(wave * 64 + g8 * 8) * 64]);
#pragma unroll
    for (int g8 = 0; g8 < 8; ++g8)
        GLL(Wp1 + 64 + (size_t)g8 * 8 * D_, &Bs[1][(wave * 64 + g8 * 8) * 64]);
    asm volatile("s_waitcnt vmcnt(16)" ::: "memory");   // A landed (oldest 2)
    __builtin_amdgcn_s_barrier();                        // Asm visible to all waves

    // per-wave 2-deep pipelined k-loop (8 steps of BK=64)
    #define KLOOP(accv, Wp)                                                           \
        for (int ks = 0; ks < 8; ++ks) {                                              \
            if (ks < 7) asm volatile("s_waitcnt vmcnt(8)" ::: "memory");              \
            else        asm volatile("s_waitcnt vmcnt(0)" ::: "memory");              \
            __builtin_amdgcn_sched_barrier(0);                                        \
            _Pragma("unroll")                                                         \
            for (int kc = 0; kc < 2; ++kc) {                                          \
                bf16x8 af = *(const bf16x8*)&Asm[l15 * 512 +                          \
                                                 ((ks * 8 + kc * 4 + quad) ^ swz) * 8];\
                _Pragma("unroll")                                                     \
                for (int nt = 0; nt < 4; ++nt) {                                      \
                    bf16x8 bf = *(const bf16x8*)&Bs[ks & 1][(wave * 64 + nt * 16 + l15) * 64 + \
                                                            ((kc * 4 + quad) ^ swz) * 8];      \
                    accv[nt] = __builtin_amdgcn_mfma_f32_16x16x32_bf16(af, bf, accv[nt], 0, 0, 0); \
                }                                                                     \
            }                                                                         \
            __builtin_amdgcn_sched_barrier(0);                                        \
            if (ks < 6) {                                                             \
                _Pragma("unroll")                                                     \
                for (int g8 = 0; g8 < 8; ++g8)                                        \
                    GLL(Wp + (ks + 2) * 64 + (size_t)g8 * 8 * D_,                     \
                        &Bs[ks & 1][(wave * 64 + g8 * 8) * 64]);                      \
            }                                                                         \
        }

    // row stats over vals[4][4] -> muv[4], rsv[4]
    #define ROWSTATS(vals, muv, rsv)                                                  \
        {                                                                             \
            __builtin_amdgcn_s_barrier();                                             \
            float s_[4] = {0.f, 0.f, 0.f, 0.f}, s2_[4] = {0.f, 0.f, 0.f, 0.f};        \
            _Pragma("unroll")                                                         \
            for (int nt = 0; nt < 4; ++nt)                                            \
                _Pragma("unroll")                                                     \
                for (int r = 0; r < 4; ++r) {                                         \
                    s_[r] += vals[nt][r]; s2_[r] += vals[nt][r] * vals[nt][r];        \
                }                                                                     \
            _Pragma("unroll")                                                         \
            for (int off = 1; off < 16; off <<= 1)                                    \
                _Pragma("unroll")                                                     \
                for (int r = 0; r < 4; ++r) {                                         \
                    s_[r] += __shfl_xor(s_[r], off); s2_[r] += __shfl_xor(s2_[r], off); \
                }                                                                     \
            if (l15 == 0) {                                                           \
                _Pragma("unroll")                                                     \
                for (int r = 0; r < 4; ++r) {                                         \
                    redS[quad * 4 + r][wave] = s_[r]; redS2[quad * 4 + r][wave] = s2_[r]; \
                }                                                                     \
            }                                                                         \
            asm volatile("s_waitcnt lgkmcnt(0)" ::: "memory");                        \
            __builtin_amdgcn_s_barrier();                                             \
            _Pragma("unroll")                                                         \
            for (int r = 0; r < 4; ++r) {                                             \
                float ss = 0.f, ss2 = 0.f;                                            \
                _Pragma("unroll")                                                     \
                for (int w = 0; w < 8; ++w) {                                         \
                    ss += redS[quad * 4 + r][w]; ss2 += redS2[quad * 4 + r][w];       \
                }                                                                     \
                muv[r] = ss * (1.f / D_);                                             \
                rsv[r] = rsqrtf(ss2 * (1.f / D_) - muv[r] * muv[r] + 1e-5f);          \
            }                                                                         \
        }

    // ---- phase 1: C1 = A @ Wo^T
    f32x4 acc[4];
#pragma unroll
    for (int nt = 0; nt < 4; ++nt)
#pragma unroll
        for (int r = 0; r < 4; ++r) acc[nt][r] = 0.f;
    KLOOP(acc, Wp1)

    // ---- issue phase-2 W staging NOW (hides under epilogue; Bs per-wave free)
    const unsigned short* Wp2 = g.W2 + (size_t)(wave * 64 + srow) * D_ + (schunk ^ srow) * 8;
#pragma unroll
    for (int g8 = 0; g8 < 8; ++g8)
        GLL(Wp2 + (size_t)g8 * 8 * D_, &Bs[0][(wave * 64 + g8 * 8) * 64]);
#pragma unroll
    for (int g8 = 0; g8 < 8; ++g8)
        GLL(Wp2 + 64 + (size_t)g8 * 8 * D_, &Bs[1][(wave * 64 + g8 * 8) * 64]);

    // hoist LN2 params + KAN coeffs per nt (latency hides under ROWSTATS)
    float c0v[4], c1v[4], w2v[4], b2v[4];
#pragma unroll
    for (int nt = 0; nt < 4; ++nt) {
        int n = wave * 64 + nt * 16 + l15;
        c0v[nt] = g.ic[n * 5 + 0];
        c1v[nt] = g.ic[n * 5 + 1];
        w2v[nt] = g.w2a[n];
        b2v[nt] = g.b2a[n];
    }

    // ---- epilogue 1: tv = acc + bias + res (regs only)
    float tv[4][4];
#pragma unroll
    for (int nt = 0; nt < 4; ++nt) {
        int n = wave * 64 + nt * 16 + l15;
        float bv = g.bias1[n];
#pragma unroll
        for (int r = 0; r < 4; ++r)
            tv[nt][r] = acc[nt][r] + bv + g.res[(size_t)(m0 + quad * 4 + r) * D_ + n];
    }

    float mu2[4], rs2[4];
    ROWSTATS(tv, mu2, rs2)

    // ---- KAN inner (closed-form uniform B-spline) -> Asm LDS (swizzled)
#pragma unroll
    for (int nt = 0; nt < 4; ++nt) {
        int n = wave * 64 + nt * 16 + l15;
        int gch = n >> 3;                      // global k-chunk
#pragma unroll
        for (int r = 0; r < 4; ++r) {
            int row = quad * 4 + r;
            float zv = (tv[nt][r] - mu2[r]) * rs2[r] * w2v[nt] + b2v[nt];
            Asm[row * 512 + (gch ^ (row & 7)) * 8 + (n & 7)] =
                f2us(kan_fast(zv, c0v[nt], c1v[nt]));
        }
    }
    asm volatile("s_waitcnt lgkmcnt(0)" ::: "memory");
    __builtin_amdgcn_s_barrier();              // inner visible to all waves
    __builtin_amdgcn_sched_barrier(0);

    // ---- phase 2: C2 = inner @ oc^T + tv
    f32x4 acc2[4];
#pragma unroll
    for (int nt = 0; nt < 4; ++nt)
#pragma unroll
        for (int r = 0; r < 4; ++r) acc2[nt][r] = 0.f;
    KLOOP(acc2, Wp2)

    float tv2[4][4];
#pragma unroll
    for (int nt = 0; nt < 4; ++nt)
#pragma unroll
        for (int r = 0; r < 4; ++r) tv2[nt][r] = acc2[nt][r] + tv[nt][r];

    float mu3[4], rs3[4];
    ROWSTATS(tv2, mu3, rs3)

    float yv[4][4];
#pragma unroll
    for (int nt = 0; nt < 4; ++nt) {
        int n = wave * 64 + nt * 16 + l15;
#pragma unroll
        for (int r = 0; r < 4; ++r) {
            float v = (tv2[nt][r] - mu3[r]) * rs3[r] * g.w3[n] + g.b3[n];
            yv[nt][r] = v;
            if (LAST) g.outp[(size_t)(m0 + quad * 4 + r) * D_ + n] = v;
            else      g.srcf[(size_t)(m0 + quad * 4 + r) * D_ + n] = v;
        }
    }

    if (!LAST) {
        float mu1[4], rs1[4];
        ROWSTATS(yv, mu1, rs1)
#pragma unroll
        for (int nt = 0; nt < 4; ++nt) {
            int n = wave * 64 + nt * 16 + l15;
#pragma unroll
            for (int r = 0; r < 4; ++r)
                g.zb[(size_t)(m0 + quad * 4 + r) * D_ + n] =
                    f2us((yv[nt][r] - mu1[r]) * rs1[r] * g.w1n[n] + g.b1n[n]);
        }
    }
    #undef KLOOP
    #undef ROWSTATS
}

// ---------- MFMA flash attention, SWAPPED QK^T, packed P-writes, PAIR-UNROLLED ----
// 4 LDS buffers, kv-tiles processed in pairs: barriers 32->16, counted-vmcnt
// waits 16->8, 2x compute per synchronization region.
__global__ __launch_bounds__(256) void attn_k(const unsigned short* __restrict__ Q,
                                              const unsigned short* __restrict__ K,
                                              const unsigned short* __restrict__ vt,
                                              const unsigned short* __restrict__ R,
                                              const int* __restrict__ mask,
                                              unsigned short* __restrict__ O) {
    __shared__ unsigned short Ks[4][64 * 64];    // 32 KB
    __shared__ unsigned short Vts[4][64 * 64];   // 32 KB
    __shared__ unsigned short Ps[4][16][72];
    __shared__ float Ms[1024];

    int bh = blockIdx.x;
    int b = bh >> 3, h = bh & 7;
    int qt0 = blockIdx.y * 64;
    int t = threadIdx.x, wave = t >> 6, lane = t & 63;
    int l15 = lane & 15, quad = lane >> 4;
    int qw0 = qt0 + wave * 16;

    const unsigned short* Qrow = Q + ((size_t)(b * S_ + qw0 + l15) * H_ + h) * DH_;
    bf16x8 qf[2];
    qf[0] = *(const bf16x8*)(Qrow + quad * 8);
    qf[1] = *(const bf16x8*)(Qrow + 32 + quad * 8);

#pragma unroll
    for (int u = 0; u < 4; ++u)
        Ms[u * 256 + t] = mask[b * S_ + u * 256 + t] ? 0.f : -1e10f;
    asm volatile("s_waitcnt lgkmcnt(0)" ::: "memory");

    float lsum = 0.f;                    // sum over k for q = l15
    f32x4 acc_o[4];
#pragma unroll
    for (int dt = 0; dt < 4; ++dt)
#pragma unroll
        for (int r = 0; r < 4; ++r) acc_o[dt][r] = 0.f;

    int lro = lane >> 3;
    int cglob = (lane & 7) ^ lro;
    const unsigned short* kgp0 =
        K + ((size_t)(b * S_ + wave * 16 + lro) * H_ + h) * DH_ + cglob * 8;
    const unsigned short* vgp0 =
        vt + (size_t)(b * 512 + h * 64 + wave * 16 + lro) * 1024 + cglob * 8;
    int swz = l15 & 7;
    const float SC = 0.125f * 1.44269504089f;

    #define ASTAGE(buf, kt)                                                         \
        do {                                                                        \
            GLL(kgp0 + (size_t)(kt) * 64 * 512,           &Ks[buf][(wave * 16) * 64]);     \
            GLL(kgp0 + (size_t)(kt) * 64 * 512 + 8 * 512, &Ks[buf][(wave * 16 + 8) * 64]); \
            GLL(vgp0 + (kt) * 64,                         &Vts[buf][(wave * 16) * 64]);    \
            GLL(vgp0 + (kt) * 64 + 8 * 1024,              &Vts[buf][(wave * 16 + 8) * 64]);\
        } while (0)

    ASTAGE(0, 0);
    ASTAGE(1, 1);

    for (int ktp = 0; ktp < 8; ++ktp) {
        int kt = ktp * 2;
        int b0 = (ktp & 1) * 2;        // buffers holding this pair
        if (ktp < 7) {
            ASTAGE(b0 ^ 2, kt + 2);    // stage next pair into the pair consumed at ktp-1
            ASTAGE((b0 ^ 2) + 1, kt + 3);
            asm volatile("s_waitcnt vmcnt(8)" ::: "memory");   // current pair landed
        } else {
            asm volatile("s_waitcnt vmcnt(0)" ::: "memory");
        }
        __builtin_amdgcn_s_barrier();
        __builtin_amdgcn_sched_barrier(0);

#pragma unroll
        for (int u = 0; u < 2; ++u) {
            int ktc = kt + u;
            int bu = b0 + u;

            // S^T = K @ Q^T
            f32x4 accs[4];
#pragma unroll
            for (int jt = 0; jt < 4; ++jt)
#pragma unroll
                for (int r = 0; r < 4; ++r) accs[jt][r] = 0.f;
            __builtin_amdgcn_s_setprio(1);
#pragma unroll
            for (int kc = 0; kc < 2; ++kc) {
                int ch = ((kc * 4 + quad) ^ swz) * 8;
#pragma unroll
                for (int jt = 0; jt < 4; ++jt) {
                    bf16x8 kf = *(const bf16x8*)&Ks[bu][(jt * 16 + l15) * 64 + ch];
                    accs[jt] = __builtin_amdgcn_mfma_f32_16x16x32_bf16(kf, qf[kc], accs[jt], 0, 0, 0);
                }
            }
            __builtin_amdgcn_s_setprio(0);

            // softmax-lite; pack 4 bf16 -> one b64 write per jt
#pragma unroll
            for (int jt = 0; jt < 4; ++jt) {
                int kb = ktc * 64 + jt * 16 + quad * 4;
                float p0 = __builtin_amdgcn_exp2f(accs[jt][0] * SC + Ms[kb + 0]);
                float p1 = __builtin_amdgcn_exp2f(accs[jt][1] * SC + Ms[kb + 1]);
                float p2 = __builtin_amdgcn_exp2f(accs[jt][2] * SC + Ms[kb + 2]);
                float p3 = __builtin_amdgcn_exp2f(accs[jt][3] * SC + Ms[kb + 3]);
                lsum += (p0 + p1) + (p2 + p3);
                uint2 pk;
                pk.x = __builtin_amdgcn_perm(__float_as_uint(p1), __float_as_uint(p0), 0x07060302u);
                pk.y = __builtin_amdgcn_perm(__float_as_uint(p3), __float_as_uint(p2), 0x07060302u);
                *(uint2*)&Ps[wave][l15][jt * 16 + quad * 4] = pk;
            }

            // O += P @ V
            __builtin_amdgcn_s_setprio(1);
#pragma unroll
            for (int kc = 0; kc < 2; ++kc) {
                bf16x8 pf = *(const bf16x8*)&Ps[wave][l15][kc * 32 + quad * 8];
                int ch = ((kc * 4 + quad) ^ swz) * 8;
#pragma unroll
                for (int dt = 0; dt < 4; ++dt) {
                    bf16x8 vf = *(const bf16x8*)&Vts[bu][(dt * 16 + l15) * 64 + ch];
                    acc_o[dt] = __builtin_amdgcn_mfma_f32_16x16x32_bf16(pf, vf, acc_o[dt], 0, 0, 0);
                }
            }
            __builtin_amdgcn_s_setprio(0);
        }

        __builtin_amdgcn_sched_barrier(0);
        __builtin_amdgcn_s_barrier();
    }
    #undef ASTAGE

    lsum += __shfl_xor(lsum, 16);
    lsum += __shfl_xor(lsum, 32);

#pragma unroll
    for (int r = 0; r < 4; ++r) {
        int qq = quad * 4 + r;
        int q = qw0 + qq;
        float inv = 1.f / __shfl(lsum, qq);
        const unsigned short* Rr = R + ((size_t)(b * S_ + q) * H_ + h) * DH_;
        unsigned short* Or = O + ((size_t)(b * S_ + q) * H_ + h) * DH_;
#pragma unroll
        for (int dt = 0; dt < 4; ++dt) {
            int d = dt * 16 + l15;
            Or[d] = f2us(acc_o[dt][r] * inv * us2f(Rr[d]));
        }
    }
}

extern "C" void kernel_launch(void* const* d_in, const int* in_sizes, int n_in,
                              void* d_out, int out_size, void* d_ws, size_t ws_size,
                              hipStream_t stream) {
    const float* src  = (const float*)d_in[0];
    const float* ln1w = (const float*)d_in[1];
    const float* ln1b = (const float*)d_in[2];
    const float* ln2w = (const float*)d_in[3];
    const float* ln2b = (const float*)d_in[4];
    const float* ln3w = (const float*)d_in[5];
    const float* ln3b = (const float*)d_in[6];
    const float* wq   = (const float*)d_in[7];
    const float* wqb  = (const float*)d_in[8];
    const float* wk   = (const float*)d_in[9];
    const float* wkb  = (const float*)d_in[10];
    const float* wv   = (const float*)d_in[11];
    const float* wvb  = (const float*)d_in[12];
    const float* wr   = (const float*)d_in[13];
    const float* wrb  = (const float*)d_in[14];
    const float* wo   = (const float*)d_in[15];
    const float* wob  = (const float*)d_in[16];
    const float* ic   = (const float*)d_in[17];
    const float* oc   = (const float*)d_in[18];
    const int* mask   = (const int*)d_in[19];
    float* out = (float*)d_out;

    // ws: srcf 8MB | zb 4 | q 4 | k 4 | v 4 | r 4 | cw24 12  = 40MB
    float* srcf = (float*)d_ws;
    unsigned short* zb = (unsigned short*)(srcf + NT);
    unsigned short* qb = zb + NT;
    unsigned short* kb = qb + NT;
    unsigned short* vb = kb + NT;   // V transposed: vt[(b*512+h*64+d)*1024+s]
    unsigned short* rb = vb + NT;
    unsigned short* cw = rb + NT;   // 24 matrices: (l*6 + {q,k,v,r,o,oc}) * DD

    PreArgs pa;
    pa.w[0] = wq; pa.w[1] = wk; pa.w[2] = wv;
    pa.w[3] = wr; pa.w[4] = wo; pa.w[5] = oc;
    pa.cw = cw; pa.src = src; pa.ln1w = ln1w; pa.ln1b = ln1b;
    pa.srcf = srcf; pa.z = zb;
    pre_k<<<dim3(6144 + NTOK / 4), dim3(256), 0, stream>>>(pa);

    for (int l = 0; l < L_; ++l) {
        unsigned short* cwl = cw + (size_t)l * 6 * DD;

        MGemm128Args ga;
        ga.A = zb;
        ga.W[0] = cwl + 0 * DD; ga.bias[0] = wqb + l * D_; ga.C[0] = qb; ga.tflag[0] = 0;
        ga.W[1] = cwl + 1 * DD; ga.bias[1] = wkb + l * D_; ga.C[1] = kb; ga.tflag[1] = 0;
        ga.W[2] = cwl + 2 * DD; ga.bias[2] = wvb + l * D_; ga.C[2] = vb; ga.tflag[2] = 1;
        ga.W[3] = cwl + 3 * DD; ga.bias[3] = wrb + l * D_; ga.C[3] = rb; ga.tflag[3] = 0;
        mgemm128_k<<<dim3(4, 32, 4), dim3(256), 0, stream>>>(ga);

        attn_k<<<dim3(32, 16), dim3(256), 0, stream>>>(qb, kb, vb, rb, mask, zb);

        GFArgs gf;
        gf.A = zb; gf.W1 = cwl + 4 * DD; gf.W2 = cwl + 5 * DD;
        gf.bias1 = wob + l * D_; gf.res = srcf;
        gf.srcf = srcf; gf.outp = out; gf.zb = zb;
        gf.w2a = ln2w + l * D_; gf.b2a = ln2b + l * D_;
        gf.w3 = ln3w + l * D_; gf.b3 = ln3b + l * D_;
        gf.w1n = (l < L_ - 1) ? ln1w + (l + 1) * D_ : nullptr;
        gf.b1n = (l < L_ - 1) ? ln1b + (l + 1) * D_ : nullptr;
        gf.ic = ic + (size_t)l * D_ * 5;

        if (l < L_ - 1)
            gemmfused_k<0><<<dim3(NTOK / 16), dim3(512), 0, stream>>>(gf);
        else
            gemmfused_k<1><<<dim3(NTOK / 16), dim3(512), 0, stream>>>(gf);
    }
}